// Round 1
// baseline (525.827 us; speedup 1.0000x reference)
//
#include <hip/hip_runtime.h>
#include <math.h>

__device__ __forceinline__ float elu_f(float v) {
    return v > 0.f ? v : __expf(v) - 1.f;
}

// ---------------- CSR build (by dst) ----------------
__global__ void count_kernel(const int* __restrict__ dst, int* __restrict__ cnt, int E) {
    int e = blockIdx.x * blockDim.x + threadIdx.x;
    if (e < E) atomicAdd(&cnt[dst[e]], 1);
}

// single-block exclusive scan over n counts; writes offs[0..n], rewrites cnt_pos[i]=excl (scatter cursor)
__global__ __launch_bounds__(1024) void scan_kernel(int* __restrict__ cnt_pos, int* __restrict__ offs, int n) {
    __shared__ int wsum[16];
    int t = threadIdx.x; int lane = t & 63; int w = t >> 6;
    int carry = 0;
    for (int base = 0; base < n; base += 1024) {
        int i = base + t;
        int v = (i < n) ? cnt_pos[i] : 0;
        int x = v;
        #pragma unroll
        for (int off = 1; off < 64; off <<= 1) {
            int y = __shfl_up(x, off);
            if (lane >= off) x += y;
        }
        if (lane == 63) wsum[w] = x;
        __syncthreads();
        if (w == 0) {
            int s = (lane < 16) ? wsum[lane] : 0;
            #pragma unroll
            for (int off = 1; off < 16; off <<= 1) {
                int y = __shfl_up(s, off);
                if (lane >= off) s += y;
            }
            if (lane < 16) wsum[lane] = s;
        }
        __syncthreads();
        int wbase = (w == 0) ? 0 : wsum[w - 1];
        int incl = carry + wbase + x;
        int excl = incl - v;
        if (i < n) { offs[i] = excl; cnt_pos[i] = excl; }
        if (i == n - 1) offs[n] = incl;
        carry += wsum[15];
        __syncthreads();
    }
}

__global__ void scatter_kernel(const int* __restrict__ src, const int* __restrict__ dst,
                               int* __restrict__ pos, int* __restrict__ srt, int E) {
    int e = blockIdx.x * blockDim.x + threadIdx.x;
    if (e < E) {
        int p = atomicAdd(&pos[dst[e]], 1);
        srt[p] = src[e];
    }
}

// ---------------- GEMM1: h1 = x @ W1  [N,256]x[256,256] fp32 ----------------
__global__ __launch_bounds__(256) void gemm1_kernel(const float* __restrict__ x, const float* __restrict__ W,
                                                    float* __restrict__ h, int n) {
    __shared__ float xs[32][36];     // 32 rows x 32 k (padded stride 36)
    __shared__ float ws[32][256];    // 32 k x 256 cols
    int t = threadIdx.x;
    int rb = blockIdx.x * 32;
    int c0 = (t & 63) * 4;
    int r0 = (t >> 6) * 8;
    float acc[8][4] = {};
    for (int kc = 0; kc < 256; kc += 32) {
        {   // stage x chunk
            int r = t >> 3, kk = (t & 7) * 4;
            int gr = rb + r;
            float4 v = make_float4(0.f, 0.f, 0.f, 0.f);
            if (gr < n) v = *(const float4*)&x[(size_t)gr * 256 + kc + kk];
            *(float4*)&xs[r][kk] = v;
        }
        #pragma unroll
        for (int i = 0; i < 8; i++) {   // stage W chunk (2048 float4s / 256 threads)
            int idx = t + i * 256;
            int wr = idx >> 6;
            int wc = (idx & 63) * 4;
            *(float4*)&ws[wr][wc] = *(const float4*)&W[(size_t)(kc + wr) * 256 + wc];
        }
        __syncthreads();
        #pragma unroll
        for (int k = 0; k < 32; k += 4) {
            float4 w0 = *(float4*)&ws[k + 0][c0];
            float4 w1 = *(float4*)&ws[k + 1][c0];
            float4 w2 = *(float4*)&ws[k + 2][c0];
            float4 w3 = *(float4*)&ws[k + 3][c0];
            #pragma unroll
            for (int r = 0; r < 8; r++) {
                float4 xv = *(float4*)&xs[r0 + r][k];
                acc[r][0] += xv.x * w0.x + xv.y * w1.x + xv.z * w2.x + xv.w * w3.x;
                acc[r][1] += xv.x * w0.y + xv.y * w1.y + xv.z * w2.y + xv.w * w3.y;
                acc[r][2] += xv.x * w0.z + xv.y * w1.z + xv.z * w2.z + xv.w * w3.z;
                acc[r][3] += xv.x * w0.w + xv.y * w1.w + xv.z * w2.w + xv.w * w3.w;
            }
        }
        __syncthreads();
    }
    #pragma unroll
    for (int r = 0; r < 8; r++) {
        int gr = rb + r0 + r;
        if (gr < n) *(float4*)&h[(size_t)gr * 256 + c0] = *(float4*)&acc[r][0];
    }
}

// ---------------- el1/er1: per-node attention logits, 8 heads x 32 dims ----------------
__global__ __launch_bounds__(256) void elr1_kernel(const float* __restrict__ h1,
                                                   const float* __restrict__ al1, const float* __restrict__ ar1,
                                                   float* __restrict__ el1, float* __restrict__ er1, int n) {
    int t = threadIdx.x; int lane = t & 63;
    int node = blockIdx.x * 4 + (t >> 6);
    if (node >= n) return;
    float4 hv = *(const float4*)&h1[(size_t)node * 256 + lane * 4];
    float4 av = *(const float4*)&al1[lane * 4];   // al1 is [8][32] = 256 floats; lane*4 spans it
    float4 rv = *(const float4*)&ar1[lane * 4];
    float pl = hv.x * av.x + hv.y * av.y + hv.z * av.z + hv.w * av.w;
    float pr = hv.x * rv.x + hv.y * rv.y + hv.z * rv.z + hv.w * rv.w;
    #pragma unroll
    for (int mask = 1; mask < 8; mask <<= 1) {
        pl += __shfl_xor(pl, mask);
        pr += __shfl_xor(pr, mask);
    }
    if ((lane & 7) == 0) {
        el1[node * 8 + (lane >> 3)] = pl;
        er1[node * 8 + (lane >> 3)] = pr;
    }
}

// ---------------- layer-1 aggregation + bias + ELU -> x1 ----------------
// one wave per node; 8 heads x 32 dims; lane l owns dims [4l,4l+4), head = l>>3
__global__ __launch_bounds__(256) void agg1_kernel(const float* __restrict__ h1, const float* __restrict__ el1,
                                                   const float* __restrict__ er1, const float* __restrict__ b1,
                                                   const int* __restrict__ offs, const int* __restrict__ srt,
                                                   float* __restrict__ x1, int n) {
    int t = threadIdx.x; int lane = t & 63;
    int node = blockIdx.x * 4 + (t >> 6);
    if (node >= n) return;
    int beg = offs[node], end = offs[node + 1];
    // pass 1: per-head max over incoming edges (8 edges x 8 heads per chunk)
    int headp = lane & 7;
    float er_p = er1[node * 8 + headp];
    float m = -INFINITY;
    for (int e0 = beg; e0 < end; e0 += 8) {
        int e = e0 + (lane >> 3);
        if (e < end) {
            int s = srt[e];
            float ev = el1[s * 8 + headp] + er_p;   // leaky slope 1.0 == identity
            m = fmaxf(m, ev);
        }
    }
    #pragma unroll
    for (int mask = 8; mask < 64; mask <<= 1) m = fmaxf(m, __shfl_xor(m, mask));
    int head = lane >> 3;
    float mh = __shfl(m, head);   // lane 'head' holds head 'head''s max
    // pass 2: exp-sum + weighted accumulate (divide at end)
    float er_h = er1[node * 8 + head];
    float4 acc = make_float4(0.f, 0.f, 0.f, 0.f);
    float dsum = 0.f;
    for (int e = beg; e < end; e++) {
        int s = srt[e];
        float ev = el1[s * 8 + head] + er_h;
        float ex = __expf(ev - mh);
        dsum += ex;
        float4 hv = *(const float4*)&h1[(size_t)s * 256 + lane * 4];
        acc.x += ex * hv.x; acc.y += ex * hv.y; acc.z += ex * hv.z; acc.w += ex * hv.w;
    }
    float inv = dsum > 0.f ? 1.f / dsum : 0.f;
    float4 bv = *(const float4*)&b1[lane * 4];
    float4 o;
    o.x = elu_f(acc.x * inv + bv.x);
    o.y = elu_f(acc.y * inv + bv.y);
    o.z = elu_f(acc.z * inv + bv.z);
    o.w = elu_f(acc.w * inv + bv.w);
    *(float4*)&x1[(size_t)node * 256 + lane * 4] = o;
}

// ---------------- GEMM2: h2 = x1 @ W2 [N,256]x[256,16] + fused el2/er2 ----------------
__global__ __launch_bounds__(256) void gemm2_kernel(const float* __restrict__ x1, const float* __restrict__ W2,
                                                    const float* __restrict__ al2, const float* __restrict__ ar2,
                                                    float* __restrict__ h2, float* __restrict__ el2,
                                                    float* __restrict__ er2, int n) {
    __shared__ float xs[16][260];
    int t = threadIdx.x;
    int nb = blockIdx.x * 16;
    #pragma unroll
    for (int i = 0; i < 4; i++) {
        int idx = t + i * 256;
        int r = idx >> 6, c4 = idx & 63;
        int gr = nb + r;
        float4 v = make_float4(0.f, 0.f, 0.f, 0.f);
        if (gr < n) v = *(const float4*)&x1[(size_t)gr * 256 + c4 * 4];
        *(float4*)&xs[r][c4 * 4] = v;
    }
    __syncthreads();
    int r = t >> 4, c = t & 15;
    float acc = 0.f;
    #pragma unroll 4
    for (int k = 0; k < 256; k += 4) {
        float4 xv = *(const float4*)&xs[r][k];
        acc += xv.x * W2[(k + 0) * 16 + c] + xv.y * W2[(k + 1) * 16 + c]
             + xv.z * W2[(k + 2) * 16 + c] + xv.w * W2[(k + 3) * 16 + c];
    }
    float pl = acc * al2[c];
    float pr = acc * ar2[c];
    #pragma unroll
    for (int mask = 1; mask < 16; mask <<= 1) {
        pl += __shfl_xor(pl, mask);
        pr += __shfl_xor(pr, mask);
    }
    int gr = nb + r;
    if (gr < n) {
        h2[(size_t)gr * 16 + c] = acc;
        if (c == 0) { el2[gr] = pl; er2[gr] = pr; }
    }
}

// ---------------- layer-2 aggregation + bias + ELU -> out ----------------
// one wave per node; 4 edge-groups x 16 dims
__global__ __launch_bounds__(256) void agg2_kernel(const float* __restrict__ h2, const float* __restrict__ el2,
                                                   const float* __restrict__ er2, const float* __restrict__ b2,
                                                   const int* __restrict__ offs, const int* __restrict__ srt,
                                                   float* __restrict__ out, int n) {
    int t = threadIdx.x; int lane = t & 63;
    int node = blockIdx.x * 4 + (t >> 6);
    if (node >= n) return;
    int beg = offs[node], end = offs[node + 1];
    int dim = lane & 15, eg = lane >> 4;
    float er_n = er2[node];
    float m = -INFINITY;
    for (int e0 = beg; e0 < end; e0 += 4) {
        int e = e0 + eg;
        if (e < end) {
            float ev = el2[srt[e]] + er_n;
            ev = fmaxf(ev, 0.2f * ev);   // leaky 0.2
            m = fmaxf(m, ev);
        }
    }
    m = fmaxf(m, __shfl_xor(m, 16));
    m = fmaxf(m, __shfl_xor(m, 32));
    float acc = 0.f, dsum = 0.f;
    for (int e0 = beg; e0 < end; e0 += 4) {
        int e = e0 + eg;
        if (e < end) {
            int s = srt[e];
            float ev = el2[s] + er_n;
            ev = fmaxf(ev, 0.2f * ev);
            float ex = __expf(ev - m);
            dsum += ex;
            acc += ex * h2[(size_t)s * 16 + dim];
        }
    }
    acc += __shfl_xor(acc, 16); acc += __shfl_xor(acc, 32);
    dsum += __shfl_xor(dsum, 16); dsum += __shfl_xor(dsum, 32);
    float inv = dsum > 0.f ? 1.f / dsum : 0.f;
    float o = elu_f(acc * inv + b2[dim]);
    if (lane < 16) out[(size_t)node * 16 + dim] = o;
}

extern "C" void kernel_launch(void* const* d_in, const int* in_sizes, int n_in,
                              void* d_out, int out_size, void* d_ws, size_t ws_size,
                              hipStream_t stream) {
    const float* x   = (const float*)d_in[0];
    const int*   src = (const int*)d_in[1];
    const int*   dst = (const int*)d_in[2];
    const float* W1  = (const float*)d_in[3];
    const float* al1 = (const float*)d_in[4];
    const float* ar1 = (const float*)d_in[5];
    const float* b1  = (const float*)d_in[6];
    const float* W2  = (const float*)d_in[7];
    const float* al2 = (const float*)d_in[8];
    const float* ar2 = (const float*)d_in[9];
    const float* b2  = (const float*)d_in[10];
    const int N = in_sizes[0] / 256;
    const int E = in_sizes[1];

    char* wsp = (char*)d_ws;
    size_t off = 0;
    auto alloc = [&](size_t bytes) -> void* {
        void* p = wsp + off;
        off = (off + bytes + 255) & ~(size_t)255;
        return p;
    };
    float* h1  = (float*)alloc((size_t)N * 256 * 4);
    float* x1  = (float*)alloc((size_t)N * 256 * 4);
    float* el1 = (float*)alloc((size_t)N * 8 * 4);
    float* er1 = (float*)alloc((size_t)N * 8 * 4);
    float* h2  = (float*)alloc((size_t)N * 16 * 4);
    float* el2 = (float*)alloc((size_t)N * 4);
    float* er2 = (float*)alloc((size_t)N * 4);
    int*   offs = (int*)alloc((size_t)(N + 1) * 4);
    int*   pos  = (int*)alloc((size_t)N * 4);
    int*   srt  = (int*)alloc((size_t)E * 4);

    hipMemsetAsync(pos, 0, (size_t)N * 4, stream);
    count_kernel<<<(E + 255) / 256, 256, 0, stream>>>(dst, pos, E);
    scan_kernel<<<1, 1024, 0, stream>>>(pos, offs, N);
    scatter_kernel<<<(E + 255) / 256, 256, 0, stream>>>(src, dst, pos, srt, E);

    gemm1_kernel<<<(N + 31) / 32, 256, 0, stream>>>(x, W1, h1, N);
    elr1_kernel<<<(N + 3) / 4, 256, 0, stream>>>(h1, al1, ar1, el1, er1, N);
    agg1_kernel<<<(N + 3) / 4, 256, 0, stream>>>(h1, el1, er1, b1, offs, srt, x1, N);
    gemm2_kernel<<<(N + 15) / 16, 256, 0, stream>>>(x1, W2, al2, ar2, h2, el2, er2, N);
    agg2_kernel<<<(N + 3) / 4, 256, 0, stream>>>(h2, el2, er2, b2, offs, srt, (float*)d_out, N);
}

// Round 2
// 390.121 us; speedup vs baseline: 1.3479x; 1.3479x over previous
//
#include <hip/hip_runtime.h>
#include <math.h>

typedef __attribute__((ext_vector_type(8))) short short8;
typedef __attribute__((ext_vector_type(4))) float f32x4;

__device__ __forceinline__ float elu_f(float v) {
    return v > 0.f ? v : __expf(v) - 1.f;
}

__device__ __forceinline__ unsigned short f2bf(float f) {
    unsigned u = __float_as_uint(f);
    unsigned r = (u + 0x7FFF + ((u >> 16) & 1)) >> 16;   // round-to-nearest-even
    return (unsigned short)r;
}

// ---------------- CSR build (by dst) ----------------
__global__ void count_kernel(const int* __restrict__ dst, int* __restrict__ cnt, int E) {
    int e = blockIdx.x * blockDim.x + threadIdx.x;
    if (e < E) atomicAdd(&cnt[dst[e]], 1);
}

// single-block exclusive scan over n counts; writes offs[0..n], rewrites cnt_pos[i]=excl (scatter cursor)
__global__ __launch_bounds__(1024) void scan_kernel(int* __restrict__ cnt_pos, int* __restrict__ offs, int n) {
    __shared__ int wsum[16];
    int t = threadIdx.x; int lane = t & 63; int w = t >> 6;
    int carry = 0;
    for (int base = 0; base < n; base += 1024) {
        int i = base + t;
        int v = (i < n) ? cnt_pos[i] : 0;
        int x = v;
        #pragma unroll
        for (int off = 1; off < 64; off <<= 1) {
            int y = __shfl_up(x, off);
            if (lane >= off) x += y;
        }
        if (lane == 63) wsum[w] = x;
        __syncthreads();
        if (w == 0) {
            int s = (lane < 16) ? wsum[lane] : 0;
            #pragma unroll
            for (int off = 1; off < 16; off <<= 1) {
                int y = __shfl_up(s, off);
                if (lane >= off) s += y;
            }
            if (lane < 16) wsum[lane] = s;
        }
        __syncthreads();
        int wbase = (w == 0) ? 0 : wsum[w - 1];
        int incl = carry + wbase + x;
        int excl = incl - v;
        if (i < n) { offs[i] = excl; cnt_pos[i] = excl; }
        if (i == n - 1) offs[n] = incl;
        carry += wsum[15];
        __syncthreads();
    }
}

__global__ void scatter_kernel(const int* __restrict__ src, const int* __restrict__ dst,
                               int* __restrict__ pos, int* __restrict__ srt, int E) {
    int e = blockIdx.x * blockDim.x + threadIdx.x;
    if (e < E) {
        int p = atomicAdd(&pos[dst[e]], 1);
        srt[p] = src[e];
    }
}

// ---------------- W1^T -> bf16 precompute ----------------
__global__ __launch_bounds__(256) void w1t_kernel(const float* __restrict__ W1, unsigned short* __restrict__ W1t) {
    int t = threadIdx.x;
    int nidx = blockIdx.x;   // output col index of h (0..255)
    W1t[nidx * 256 + t] = f2bf(W1[t * 256 + nidx]);
}

// ---------------- GEMM1: h1 = x @ W1  [N,256]x[256,256] via bf16 MFMA ----------------
// block = 256 thr / 4 waves; tile = 64 rows x 256 cols; K-step 32.
// LDS stride 40 bf16 -> b128 staging writes + frag reads, conflict-free.
#define STR1 40
__global__ __launch_bounds__(256) void gemm1_mfma(const float* __restrict__ x,
                                                  const unsigned short* __restrict__ W1t,
                                                  float* __restrict__ h, int n) {
    __shared__ unsigned short As[64 * STR1];
    __shared__ unsigned short Bs[256 * STR1];
    int t = threadIdx.x;
    int w = t >> 6, l = t & 63;
    int rb = blockIdx.x * 64;
    f32x4 acc[16] = {};
    int ar = t >> 2;          // A-stage row 0..63
    int ak = (t & 3) * 8;     // A-stage k0
    int lr = w * 16 + (l & 15);  // frag row in LDS
    int lg = l >> 4;             // k-group (contiguous-8 layout: k = 8*g + i)
    for (int kc = 0; kc < 256; kc += 32) {
        {   // stage A (64x32), fp32 -> bf16
            int gr = rb + ar;
            float v[8];
            if (gr < n) {
                f32x4 v0 = *(const f32x4*)&x[(size_t)gr * 256 + kc + ak];
                f32x4 v1 = *(const f32x4*)&x[(size_t)gr * 256 + kc + ak + 4];
                v[0] = v0.x; v[1] = v0.y; v[2] = v0.z; v[3] = v0.w;
                v[4] = v1.x; v[5] = v1.y; v[6] = v1.z; v[7] = v1.w;
            } else {
                #pragma unroll
                for (int i = 0; i < 8; i++) v[i] = 0.f;
            }
            short8 bv;
            #pragma unroll
            for (int i = 0; i < 8; i++) bv[i] = (short)f2bf(v[i]);
            *(short8*)&As[ar * STR1 + ak] = bv;
        }
        #pragma unroll
        for (int i = 0; i < 4; i++) {   // stage B: Wt (256 cols)x(32 k), already bf16
            int idx = t + i * 256;
            int bn = idx >> 2;
            int bk = (idx & 3) * 8;
            short8 bv = *(const short8*)&W1t[(size_t)bn * 256 + kc + bk];
            *(short8*)&Bs[bn * STR1 + bk] = bv;
        }
        __syncthreads();
        short8 a = *(short8*)&As[lr * STR1 + lg * 8];
        #pragma unroll
        for (int j = 0; j < 16; j++) {
            short8 b = *(short8*)&Bs[(j * 16 + (l & 15)) * STR1 + lg * 8];
            acc[j] = __builtin_amdgcn_mfma_f32_16x16x32_bf16(a, b, acc[j], 0, 0, 0);
        }
        __syncthreads();
    }
    // epilogue: C layout col = l&15, row = 4*(l>>4)+i
    int r0 = rb + w * 16 + 4 * (l >> 4);
    int c0 = l & 15;
    #pragma unroll
    for (int j = 0; j < 16; j++) {
        #pragma unroll
        for (int i = 0; i < 4; i++) {
            int gr = r0 + i;
            if (gr < n) h[(size_t)gr * 256 + j * 16 + c0] = acc[j][i];
        }
    }
}

// ---------------- el1/er1: per-node attention logits, 8 heads x 32 dims ----------------
__global__ __launch_bounds__(256) void elr1_kernel(const float* __restrict__ h1,
                                                   const float* __restrict__ al1, const float* __restrict__ ar1,
                                                   float* __restrict__ el1, float* __restrict__ er1, int n) {
    int t = threadIdx.x; int lane = t & 63;
    int node = blockIdx.x * 4 + (t >> 6);
    if (node >= n) return;
    float4 hv = *(const float4*)&h1[(size_t)node * 256 + lane * 4];
    float4 av = *(const float4*)&al1[lane * 4];
    float4 rv = *(const float4*)&ar1[lane * 4];
    float pl = hv.x * av.x + hv.y * av.y + hv.z * av.z + hv.w * av.w;
    float pr = hv.x * rv.x + hv.y * rv.y + hv.z * rv.z + hv.w * rv.w;
    #pragma unroll
    for (int mask = 1; mask < 8; mask <<= 1) {
        pl += __shfl_xor(pl, mask);
        pr += __shfl_xor(pr, mask);
    }
    if ((lane & 7) == 0) {
        el1[node * 8 + (lane >> 3)] = pl;
        er1[node * 8 + (lane >> 3)] = pr;
    }
}

// ---------------- layer-1 aggregation + bias + ELU -> x1 ----------------
__global__ __launch_bounds__(256) void agg1_kernel(const float* __restrict__ h1, const float* __restrict__ el1,
                                                   const float* __restrict__ er1, const float* __restrict__ b1,
                                                   const int* __restrict__ offs, const int* __restrict__ srt,
                                                   float* __restrict__ x1, int n) {
    int t = threadIdx.x; int lane = t & 63;
    int node = blockIdx.x * 4 + (t >> 6);
    if (node >= n) return;
    int beg = offs[node], end = offs[node + 1];
    int headp = lane & 7;
    float er_p = er1[node * 8 + headp];
    float m = -INFINITY;
    for (int e0 = beg; e0 < end; e0 += 8) {
        int e = e0 + (lane >> 3);
        if (e < end) {
            int s = srt[e];
            float ev = el1[s * 8 + headp] + er_p;   // leaky slope 1.0 == identity
            m = fmaxf(m, ev);
        }
    }
    #pragma unroll
    for (int mask = 8; mask < 64; mask <<= 1) m = fmaxf(m, __shfl_xor(m, mask));
    int head = lane >> 3;
    float mh = __shfl(m, head);
    float er_h = er1[node * 8 + head];
    float4 acc = make_float4(0.f, 0.f, 0.f, 0.f);
    float dsum = 0.f;
    for (int e = beg; e < end; e++) {
        int s = srt[e];
        float ev = el1[s * 8 + head] + er_h;
        float ex = __expf(ev - mh);
        dsum += ex;
        float4 hv = *(const float4*)&h1[(size_t)s * 256 + lane * 4];
        acc.x += ex * hv.x; acc.y += ex * hv.y; acc.z += ex * hv.z; acc.w += ex * hv.w;
    }
    float inv = dsum > 0.f ? 1.f / dsum : 0.f;
    float4 bv = *(const float4*)&b1[lane * 4];
    float4 o;
    o.x = elu_f(acc.x * inv + bv.x);
    o.y = elu_f(acc.y * inv + bv.y);
    o.z = elu_f(acc.z * inv + bv.z);
    o.w = elu_f(acc.w * inv + bv.w);
    *(float4*)&x1[(size_t)node * 256 + lane * 4] = o;
}

// ---------------- GEMM2: h2 = x1 @ W2 [N,256]x[256,16] + fused el2/er2 ----------------
__global__ __launch_bounds__(256) void gemm2_kernel(const float* __restrict__ x1, const float* __restrict__ W2,
                                                    const float* __restrict__ al2, const float* __restrict__ ar2,
                                                    float* __restrict__ h2, float* __restrict__ el2,
                                                    float* __restrict__ er2, int n) {
    __shared__ float xs[16][260];
    int t = threadIdx.x;
    int nb = blockIdx.x * 16;
    #pragma unroll
    for (int i = 0; i < 4; i++) {
        int idx = t + i * 256;
        int r = idx >> 6, c4 = idx & 63;
        int gr = nb + r;
        float4 v = make_float4(0.f, 0.f, 0.f, 0.f);
        if (gr < n) v = *(const float4*)&x1[(size_t)gr * 256 + c4 * 4];
        *(float4*)&xs[r][c4 * 4] = v;
    }
    __syncthreads();
    int r = t >> 4, c = t & 15;
    float acc = 0.f;
    #pragma unroll 4
    for (int k = 0; k < 256; k += 4) {
        float4 xv = *(const float4*)&xs[r][k];
        acc += xv.x * W2[(k + 0) * 16 + c] + xv.y * W2[(k + 1) * 16 + c]
             + xv.z * W2[(k + 2) * 16 + c] + xv.w * W2[(k + 3) * 16 + c];
    }
    float pl = acc * al2[c];
    float pr = acc * ar2[c];
    #pragma unroll
    for (int mask = 1; mask < 16; mask <<= 1) {
        pl += __shfl_xor(pl, mask);
        pr += __shfl_xor(pr, mask);
    }
    int gr = nb + r;
    if (gr < n) {
        h2[(size_t)gr * 16 + c] = acc;
        if (c == 0) { el2[gr] = pl; er2[gr] = pr; }
    }
}

// ---------------- layer-2 aggregation + bias + ELU -> out ----------------
__global__ __launch_bounds__(256) void agg2_kernel(const float* __restrict__ h2, const float* __restrict__ el2,
                                                   const float* __restrict__ er2, const float* __restrict__ b2,
                                                   const int* __restrict__ offs, const int* __restrict__ srt,
                                                   float* __restrict__ out, int n) {
    int t = threadIdx.x; int lane = t & 63;
    int node = blockIdx.x * 4 + (t >> 6);
    if (node >= n) return;
    int beg = offs[node], end = offs[node + 1];
    int dim = lane & 15, eg = lane >> 4;
    float er_n = er2[node];
    float m = -INFINITY;
    for (int e0 = beg; e0 < end; e0 += 4) {
        int e = e0 + eg;
        if (e < end) {
            float ev = el2[srt[e]] + er_n;
            ev = fmaxf(ev, 0.2f * ev);
            m = fmaxf(m, ev);
        }
    }
    m = fmaxf(m, __shfl_xor(m, 16));
    m = fmaxf(m, __shfl_xor(m, 32));
    float acc = 0.f, dsum = 0.f;
    for (int e0 = beg; e0 < end; e0 += 4) {
        int e = e0 + eg;
        if (e < end) {
            int s = srt[e];
            float ev = el2[s] + er_n;
            ev = fmaxf(ev, 0.2f * ev);
            float ex = __expf(ev - m);
            dsum += ex;
            acc += ex * h2[(size_t)s * 16 + dim];
        }
    }
    acc += __shfl_xor(acc, 16); acc += __shfl_xor(acc, 32);
    dsum += __shfl_xor(dsum, 16); dsum += __shfl_xor(dsum, 32);
    float inv = dsum > 0.f ? 1.f / dsum : 0.f;
    float o = elu_f(acc * inv + b2[dim]);
    if (lane < 16) out[(size_t)node * 16 + dim] = o;
}

extern "C" void kernel_launch(void* const* d_in, const int* in_sizes, int n_in,
                              void* d_out, int out_size, void* d_ws, size_t ws_size,
                              hipStream_t stream) {
    const float* x   = (const float*)d_in[0];
    const int*   src = (const int*)d_in[1];
    const int*   dst = (const int*)d_in[2];
    const float* W1  = (const float*)d_in[3];
    const float* al1 = (const float*)d_in[4];
    const float* ar1 = (const float*)d_in[5];
    const float* b1  = (const float*)d_in[6];
    const float* W2  = (const float*)d_in[7];
    const float* al2 = (const float*)d_in[8];
    const float* ar2 = (const float*)d_in[9];
    const float* b2  = (const float*)d_in[10];
    const int N = in_sizes[0] / 256;
    const int E = in_sizes[1];

    char* wsp = (char*)d_ws;
    size_t off = 0;
    auto alloc = [&](size_t bytes) -> void* {
        void* p = wsp + off;
        off = (off + bytes + 255) & ~(size_t)255;
        return p;
    };
    float* h1  = (float*)alloc((size_t)N * 256 * 4);
    float* x1  = (float*)alloc((size_t)N * 256 * 4);
    float* el1 = (float*)alloc((size_t)N * 8 * 4);
    float* er1 = (float*)alloc((size_t)N * 8 * 4);
    float* h2  = (float*)alloc((size_t)N * 16 * 4);
    float* el2 = (float*)alloc((size_t)N * 4);
    float* er2 = (float*)alloc((size_t)N * 4);
    int*   offs = (int*)alloc((size_t)(N + 1) * 4);
    int*   pos  = (int*)alloc((size_t)N * 4);
    int*   srt  = (int*)alloc((size_t)E * 4);
    unsigned short* W1t = (unsigned short*)alloc((size_t)256 * 256 * 2);

    hipMemsetAsync(pos, 0, (size_t)N * 4, stream);
    count_kernel<<<(E + 255) / 256, 256, 0, stream>>>(dst, pos, E);
    scan_kernel<<<1, 1024, 0, stream>>>(pos, offs, N);
    scatter_kernel<<<(E + 255) / 256, 256, 0, stream>>>(src, dst, pos, srt, E);

    w1t_kernel<<<256, 256, 0, stream>>>(W1, W1t);
    gemm1_mfma<<<(N + 63) / 64, 256, 0, stream>>>(x, W1t, h1, N);
    elr1_kernel<<<(N + 3) / 4, 256, 0, stream>>>(h1, al1, ar1, el1, er1, N);
    agg1_kernel<<<(N + 3) / 4, 256, 0, stream>>>(h1, el1, er1, b1, offs, srt, x1, N);
    gemm2_kernel<<<(N + 15) / 16, 256, 0, stream>>>(x1, W2, al2, ar2, h2, el2, er2, N);
    agg2_kernel<<<(N + 3) / 4, 256, 0, stream>>>(h2, el2, er2, b2, offs, srt, (float*)d_out, N);
}

// Round 3
// 329.558 us; speedup vs baseline: 1.5956x; 1.1838x over previous
//
#include <hip/hip_runtime.h>
#include <math.h>

typedef __attribute__((ext_vector_type(8))) short short8;
typedef __attribute__((ext_vector_type(4))) short short4v;
typedef __attribute__((ext_vector_type(4))) float f32x4;

__device__ __forceinline__ float elu_f(float v) {
    return v > 0.f ? v : __expf(v) - 1.f;
}

__device__ __forceinline__ unsigned short f2bf(float f) {
    unsigned u = __float_as_uint(f);
    unsigned r = (u + 0x7FFF + ((u >> 16) & 1)) >> 16;   // round-to-nearest-even
    return (unsigned short)r;
}

__device__ __forceinline__ float bf2f(unsigned short u) {
    return __uint_as_float(((unsigned)u) << 16);
}

// ---------------- CSR build (by dst) ----------------
__global__ void count_kernel(const int* __restrict__ dst, int* __restrict__ cnt, int E) {
    int e = blockIdx.x * blockDim.x + threadIdx.x;
    if (e < E) atomicAdd(&cnt[dst[e]], 1);
}

// single-block exclusive scan over n counts; writes offs[0..n], rewrites cnt_pos[i]=excl (scatter cursor)
__global__ __launch_bounds__(1024) void scan_kernel(int* __restrict__ cnt_pos, int* __restrict__ offs, int n) {
    __shared__ int wsum[16];
    int t = threadIdx.x; int lane = t & 63; int w = t >> 6;
    int carry = 0;
    for (int base = 0; base < n; base += 1024) {
        int i = base + t;
        int v = (i < n) ? cnt_pos[i] : 0;
        int x = v;
        #pragma unroll
        for (int off = 1; off < 64; off <<= 1) {
            int y = __shfl_up(x, off);
            if (lane >= off) x += y;
        }
        if (lane == 63) wsum[w] = x;
        __syncthreads();
        if (w == 0) {
            int s = (lane < 16) ? wsum[lane] : 0;
            #pragma unroll
            for (int off = 1; off < 16; off <<= 1) {
                int y = __shfl_up(s, off);
                if (lane >= off) s += y;
            }
            if (lane < 16) wsum[lane] = s;
        }
        __syncthreads();
        int wbase = (w == 0) ? 0 : wsum[w - 1];
        int incl = carry + wbase + x;
        int excl = incl - v;
        if (i < n) { offs[i] = excl; cnt_pos[i] = excl; }
        if (i == n - 1) offs[n] = incl;
        carry += wsum[15];
        __syncthreads();
    }
}

__global__ void scatter_kernel(const int* __restrict__ src, const int* __restrict__ dst,
                               int* __restrict__ pos, int* __restrict__ srt, int E) {
    int e = blockIdx.x * blockDim.x + threadIdx.x;
    if (e < E) {
        int p = atomicAdd(&pos[dst[e]], 1);
        srt[p] = src[e];
    }
}

// ---------------- W1^T -> bf16 precompute ----------------
__global__ __launch_bounds__(256) void w1t_kernel(const float* __restrict__ W1, unsigned short* __restrict__ W1t) {
    int t = threadIdx.x;
    int nidx = blockIdx.x;   // output col index of h (0..255)
    W1t[nidx * 256 + t] = f2bf(W1[t * 256 + nidx]);
}

// ---------------- GEMM1: h1 = x @ W1  [N,256]x[256,256] via bf16 MFMA; bf16 output ----------------
#define STR1 40
__global__ __launch_bounds__(256) void gemm1_mfma(const float* __restrict__ x,
                                                  const unsigned short* __restrict__ W1t,
                                                  unsigned short* __restrict__ h, int n) {
    __shared__ unsigned short As[64 * STR1];
    __shared__ unsigned short Bs[256 * STR1];
    int t = threadIdx.x;
    int w = t >> 6, l = t & 63;
    int rb = blockIdx.x * 64;
    f32x4 acc[16] = {};
    int ar = t >> 2;          // A-stage row 0..63
    int ak = (t & 3) * 8;     // A-stage k0
    int lr = w * 16 + (l & 15);  // frag row in LDS
    int lg = l >> 4;             // k-group (contiguous-8 layout: k = 8*g + i)
    for (int kc = 0; kc < 256; kc += 32) {
        {   // stage A (64x32), fp32 -> bf16
            int gr = rb + ar;
            float v[8];
            if (gr < n) {
                f32x4 v0 = *(const f32x4*)&x[(size_t)gr * 256 + kc + ak];
                f32x4 v1 = *(const f32x4*)&x[(size_t)gr * 256 + kc + ak + 4];
                v[0] = v0.x; v[1] = v0.y; v[2] = v0.z; v[3] = v0.w;
                v[4] = v1.x; v[5] = v1.y; v[6] = v1.z; v[7] = v1.w;
            } else {
                #pragma unroll
                for (int i = 0; i < 8; i++) v[i] = 0.f;
            }
            short8 bv;
            #pragma unroll
            for (int i = 0; i < 8; i++) bv[i] = (short)f2bf(v[i]);
            *(short8*)&As[ar * STR1 + ak] = bv;
        }
        #pragma unroll
        for (int i = 0; i < 4; i++) {   // stage B: Wt (256 cols)x(32 k), already bf16
            int idx = t + i * 256;
            int bn = idx >> 2;
            int bk = (idx & 3) * 8;
            short8 bv = *(const short8*)&W1t[(size_t)bn * 256 + kc + bk];
            *(short8*)&Bs[bn * STR1 + bk] = bv;
        }
        __syncthreads();
        short8 a = *(short8*)&As[lr * STR1 + lg * 8];
        #pragma unroll
        for (int j = 0; j < 16; j++) {
            short8 b = *(short8*)&Bs[(j * 16 + (l & 15)) * STR1 + lg * 8];
            acc[j] = __builtin_amdgcn_mfma_f32_16x16x32_bf16(a, b, acc[j], 0, 0, 0);
        }
        __syncthreads();
    }
    // epilogue: C layout col = l&15, row = 4*(l>>4)+i ; emit bf16
    int r0 = rb + w * 16 + 4 * (l >> 4);
    int c0 = l & 15;
    #pragma unroll
    for (int j = 0; j < 16; j++) {
        #pragma unroll
        for (int i = 0; i < 4; i++) {
            int gr = r0 + i;
            if (gr < n) h[(size_t)gr * 256 + j * 16 + c0] = f2bf(acc[j][i]);
        }
    }
}

// ---------------- el1/er1: per-node attention logits from bf16 h1 ----------------
__global__ __launch_bounds__(256) void elr1_kernel(const unsigned short* __restrict__ h1b,
                                                   const float* __restrict__ al1, const float* __restrict__ ar1,
                                                   float* __restrict__ el1, float* __restrict__ er1, int n) {
    int t = threadIdx.x; int lane = t & 63;
    int node = blockIdx.x * 4 + (t >> 6);
    if (node >= n) return;
    short4v hv4 = *(const short4v*)&h1b[(size_t)node * 256 + lane * 4];
    float4 av = *(const float4*)&al1[lane * 4];
    float4 rv = *(const float4*)&ar1[lane * 4];
    float h0 = bf2f((unsigned short)hv4[0]), h1v = bf2f((unsigned short)hv4[1]);
    float h2v = bf2f((unsigned short)hv4[2]), h3 = bf2f((unsigned short)hv4[3]);
    float pl = h0 * av.x + h1v * av.y + h2v * av.z + h3 * av.w;
    float pr = h0 * rv.x + h1v * rv.y + h2v * rv.z + h3 * rv.w;
    #pragma unroll
    for (int mask = 1; mask < 8; mask <<= 1) {
        pl += __shfl_xor(pl, mask);
        pr += __shfl_xor(pr, mask);
    }
    if ((lane & 7) == 0) {
        el1[node * 8 + (lane >> 3)] = pl;
        er1[node * 8 + (lane >> 3)] = pr;
    }
}

// ---------------- layer-1 aggregation + bias + ELU -> x1 (fp32) ----------------
// one wave per node. Pass1: 8 edges x 8 heads. Pass2: dual-edge, half-wave per edge,
// lane owns 8 contiguous dims (bf16x8 = 16B), head = (lane&31)>>2.
__global__ __launch_bounds__(256) void agg1_kernel(const unsigned short* __restrict__ h1b,
                                                   const float* __restrict__ el1,
                                                   const float* __restrict__ er1, const float* __restrict__ b1,
                                                   const int* __restrict__ offs, const int* __restrict__ srt,
                                                   float* __restrict__ x1, int n) {
    int t = threadIdx.x; int lane = t & 63;
    int node = blockIdx.x * 4 + (t >> 6);
    if (node >= n) return;
    int beg = offs[node], end = offs[node + 1];
    // pass 1: per-head max
    int headp = lane & 7;
    float er_p = er1[node * 8 + headp];
    float m = -INFINITY;
    for (int e0 = beg; e0 < end; e0 += 8) {
        int e = e0 + (lane >> 3);
        if (e < end) {
            int s = srt[e];
            m = fmaxf(m, el1[s * 8 + headp] + er_p);   // leaky slope 1.0 == identity
        }
    }
    #pragma unroll
    for (int mask = 8; mask < 64; mask <<= 1) m = fmaxf(m, __shfl_xor(m, mask));
    // pass 2
    int q = lane & 31;          // dim-group: dims [8q, 8q+8)
    int head = q >> 2;
    int half = lane >> 5;
    float mh = __shfl(m, head);            // lane 'head' has that head's max
    float er_h = er1[node * 8 + head];
    float acc[8] = {};
    float dsum = 0.f;
    for (int e0 = beg; e0 < end; e0 += 2) {
        int e = e0 + half;
        if (e < end) {
            int s = srt[e];
            float ex = __expf(el1[s * 8 + head] + er_h - mh);
            dsum += ex;
            short8 hv = *(const short8*)&h1b[(size_t)s * 256 + q * 8];
            #pragma unroll
            for (int k = 0; k < 8; k++) acc[k] += ex * bf2f((unsigned short)hv[k]);
        }
    }
    dsum += __shfl_xor(dsum, 32);
    #pragma unroll
    for (int k = 0; k < 8; k++) acc[k] += __shfl_xor(acc[k], 32);
    if (half == 0) {
        float inv = dsum > 0.f ? 1.f / dsum : 0.f;
        f32x4 b0 = *(const f32x4*)&b1[q * 8];
        f32x4 b4 = *(const f32x4*)&b1[q * 8 + 4];
        f32x4 o0, o1;
        o0.x = elu_f(acc[0] * inv + b0.x); o0.y = elu_f(acc[1] * inv + b0.y);
        o0.z = elu_f(acc[2] * inv + b0.z); o0.w = elu_f(acc[3] * inv + b0.w);
        o1.x = elu_f(acc[4] * inv + b4.x); o1.y = elu_f(acc[5] * inv + b4.y);
        o1.z = elu_f(acc[6] * inv + b4.z); o1.w = elu_f(acc[7] * inv + b4.w);
        *(f32x4*)&x1[(size_t)node * 256 + q * 8] = o0;
        *(f32x4*)&x1[(size_t)node * 256 + q * 8 + 4] = o1;
    }
}

// ---------------- GEMM2: h2 = x1 @ W2 [N,256]x[256,16] + fused el2/er2 ----------------
__global__ __launch_bounds__(256) void gemm2_kernel(const float* __restrict__ x1, const float* __restrict__ W2,
                                                    const float* __restrict__ al2, const float* __restrict__ ar2,
                                                    float* __restrict__ h2, float* __restrict__ el2,
                                                    float* __restrict__ er2, int n) {
    __shared__ float xs[16][260];
    int t = threadIdx.x;
    int nb = blockIdx.x * 16;
    #pragma unroll
    for (int i = 0; i < 4; i++) {
        int idx = t + i * 256;
        int r = idx >> 6, c4 = idx & 63;
        int gr = nb + r;
        float4 v = make_float4(0.f, 0.f, 0.f, 0.f);
        if (gr < n) v = *(const float4*)&x1[(size_t)gr * 256 + c4 * 4];
        *(float4*)&xs[r][c4 * 4] = v;
    }
    __syncthreads();
    int r = t >> 4, c = t & 15;
    float acc = 0.f;
    #pragma unroll 4
    for (int k = 0; k < 256; k += 4) {
        float4 xv = *(const float4*)&xs[r][k];
        acc += xv.x * W2[(k + 0) * 16 + c] + xv.y * W2[(k + 1) * 16 + c]
             + xv.z * W2[(k + 2) * 16 + c] + xv.w * W2[(k + 3) * 16 + c];
    }
    float pl = acc * al2[c];
    float pr = acc * ar2[c];
    #pragma unroll
    for (int mask = 1; mask < 16; mask <<= 1) {
        pl += __shfl_xor(pl, mask);
        pr += __shfl_xor(pr, mask);
    }
    int gr = nb + r;
    if (gr < n) {
        h2[(size_t)gr * 16 + c] = acc;
        if (c == 0) { el2[gr] = pl; er2[gr] = pr; }
    }
}

// ---------------- layer-2 aggregation + bias + ELU -> out ----------------
__global__ __launch_bounds__(256) void agg2_kernel(const float* __restrict__ h2, const float* __restrict__ el2,
                                                   const float* __restrict__ er2, const float* __restrict__ b2,
                                                   const int* __restrict__ offs, const int* __restrict__ srt,
                                                   float* __restrict__ out, int n) {
    int t = threadIdx.x; int lane = t & 63;
    int node = blockIdx.x * 4 + (t >> 6);
    if (node >= n) return;
    int beg = offs[node], end = offs[node + 1];
    int dim = lane & 15, eg = lane >> 4;
    float er_n = er2[node];
    float m = -INFINITY;
    for (int e0 = beg; e0 < end; e0 += 4) {
        int e = e0 + eg;
        if (e < end) {
            float ev = el2[srt[e]] + er_n;
            ev = fmaxf(ev, 0.2f * ev);
            m = fmaxf(m, ev);
        }
    }
    m = fmaxf(m, __shfl_xor(m, 16));
    m = fmaxf(m, __shfl_xor(m, 32));
    float acc = 0.f, dsum = 0.f;
    for (int e0 = beg; e0 < end; e0 += 4) {
        int e = e0 + eg;
        if (e < end) {
            int s = srt[e];
            float ev = el2[s] + er_n;
            ev = fmaxf(ev, 0.2f * ev);
            float ex = __expf(ev - m);
            dsum += ex;
            acc += ex * h2[(size_t)s * 16 + dim];
        }
    }
    acc += __shfl_xor(acc, 16); acc += __shfl_xor(acc, 32);
    dsum += __shfl_xor(dsum, 16); dsum += __shfl_xor(dsum, 32);
    float inv = dsum > 0.f ? 1.f / dsum : 0.f;
    float o = elu_f(acc * inv + b2[dim]);
    if (lane < 16) out[(size_t)node * 16 + dim] = o;
}

extern "C" void kernel_launch(void* const* d_in, const int* in_sizes, int n_in,
                              void* d_out, int out_size, void* d_ws, size_t ws_size,
                              hipStream_t stream) {
    const float* x   = (const float*)d_in[0];
    const int*   src = (const int*)d_in[1];
    const int*   dst = (const int*)d_in[2];
    const float* W1  = (const float*)d_in[3];
    const float* al1 = (const float*)d_in[4];
    const float* ar1 = (const float*)d_in[5];
    const float* b1  = (const float*)d_in[6];
    const float* W2  = (const float*)d_in[7];
    const float* al2 = (const float*)d_in[8];
    const float* ar2 = (const float*)d_in[9];
    const float* b2  = (const float*)d_in[10];
    const int N = in_sizes[0] / 256;
    const int E = in_sizes[1];

    char* wsp = (char*)d_ws;
    size_t off = 0;
    auto alloc = [&](size_t bytes) -> void* {
        void* p = wsp + off;
        off = (off + bytes + 255) & ~(size_t)255;
        return p;
    };
    unsigned short* h1b = (unsigned short*)alloc((size_t)N * 256 * 2);
    float* x1  = (float*)alloc((size_t)N * 256 * 4);
    float* el1 = (float*)alloc((size_t)N * 8 * 4);
    float* er1 = (float*)alloc((size_t)N * 8 * 4);
    float* h2  = (float*)alloc((size_t)N * 16 * 4);
    float* el2 = (float*)alloc((size_t)N * 4);
    float* er2 = (float*)alloc((size_t)N * 4);
    int*   offs = (int*)alloc((size_t)(N + 1) * 4);
    int*   pos  = (int*)alloc((size_t)N * 4);
    int*   srt  = (int*)alloc((size_t)E * 4);
    unsigned short* W1t = (unsigned short*)alloc((size_t)256 * 256 * 2);

    hipMemsetAsync(pos, 0, (size_t)N * 4, stream);
    count_kernel<<<(E + 255) / 256, 256, 0, stream>>>(dst, pos, E);
    scan_kernel<<<1, 1024, 0, stream>>>(pos, offs, N);
    scatter_kernel<<<(E + 255) / 256, 256, 0, stream>>>(src, dst, pos, srt, E);

    w1t_kernel<<<256, 256, 0, stream>>>(W1, W1t);
    gemm1_mfma<<<(N + 63) / 64, 256, 0, stream>>>(x, W1t, h1b, N);
    elr1_kernel<<<(N + 3) / 4, 256, 0, stream>>>(h1b, al1, ar1, el1, er1, N);
    agg1_kernel<<<(N + 3) / 4, 256, 0, stream>>>(h1b, el1, er1, b1, offs, srt, x1, N);
    gemm2_kernel<<<(N + 15) / 16, 256, 0, stream>>>(x1, W2, al2, ar2, h2, el2, er2, N);
    agg2_kernel<<<(N + 3) / 4, 256, 0, stream>>>(h2, el2, er2, b2, offs, srt, (float*)d_out, N);
}

// Round 4
// 312.779 us; speedup vs baseline: 1.6811x; 1.0536x over previous
//
#include <hip/hip_runtime.h>
#include <math.h>

typedef __attribute__((ext_vector_type(8))) short short8;
typedef __attribute__((ext_vector_type(4))) float f32x4;

__device__ __forceinline__ float elu_f(float v) {
    return v > 0.f ? v : __expf(v) - 1.f;
}

__device__ __forceinline__ unsigned short f2bf(float f) {
    unsigned u = __float_as_uint(f);
    unsigned r = (u + 0x7FFF + ((u >> 16) & 1)) >> 16;   // round-to-nearest-even
    return (unsigned short)r;
}

__device__ __forceinline__ float bf2f(unsigned short u) {
    return __uint_as_float(((unsigned)u) << 16);
}

// ---------------- CSR build (by dst) ----------------
__global__ void count_kernel(const int* __restrict__ dst, int* __restrict__ cnt, int E) {
    int e = blockIdx.x * blockDim.x + threadIdx.x;
    if (e < E) atomicAdd(&cnt[dst[e]], 1);
}

// single-block exclusive scan over n counts; writes offs[0..n], rewrites cnt_pos[i]=excl (scatter cursor)
__global__ __launch_bounds__(1024) void scan_kernel(int* __restrict__ cnt_pos, int* __restrict__ offs, int n) {
    __shared__ int wsum[16];
    int t = threadIdx.x; int lane = t & 63; int w = t >> 6;
    int carry = 0;
    for (int base = 0; base < n; base += 1024) {
        int i = base + t;
        int v = (i < n) ? cnt_pos[i] : 0;
        int x = v;
        #pragma unroll
        for (int off = 1; off < 64; off <<= 1) {
            int y = __shfl_up(x, off);
            if (lane >= off) x += y;
        }
        if (lane == 63) wsum[w] = x;
        __syncthreads();
        if (w == 0) {
            int s = (lane < 16) ? wsum[lane] : 0;
            #pragma unroll
            for (int off = 1; off < 16; off <<= 1) {
                int y = __shfl_up(s, off);
                if (lane >= off) s += y;
            }
            if (lane < 16) wsum[lane] = s;
        }
        __syncthreads();
        int wbase = (w == 0) ? 0 : wsum[w - 1];
        int incl = carry + wbase + x;
        int excl = incl - v;
        if (i < n) { offs[i] = excl; cnt_pos[i] = excl; }
        if (i == n - 1) offs[n] = incl;
        carry += wsum[15];
        __syncthreads();
    }
}

__global__ void scatter_kernel(const int* __restrict__ src, const int* __restrict__ dst,
                               int* __restrict__ pos, int* __restrict__ srt, int E) {
    int e = blockIdx.x * blockDim.x + threadIdx.x;
    if (e < E) {
        int p = atomicAdd(&pos[dst[e]], 1);
        srt[p] = src[e];
    }
}

// ---------------- W1^T -> bf16 precompute (cols 0..255) ----------------
__global__ __launch_bounds__(256) void w1t_kernel(const float* __restrict__ W1, unsigned short* __restrict__ W1t) {
    int t = threadIdx.x;
    int nidx = blockIdx.x;   // output col index of h (0..255)
    W1t[nidx * 256 + t] = f2bf(W1[t * 256 + nidx]);
}

// ---------------- wl/wr -> extra bf16 B-columns 256..271 of W1t ----------------
// col 256+h = W1[:, head h dims] . al1[h]  ;  col 264+h = ... ar1[h]
__global__ __launch_bounds__(256) void wlr_kernel(const float* __restrict__ W1,
                                                  const float* __restrict__ al1, const float* __restrict__ ar1,
                                                  unsigned short* __restrict__ W1t) {
    int k = threadIdx.x;   // input-feature row 0..255
    #pragma unroll
    for (int h = 0; h < 8; h++) {
        float sl = 0.f, sr = 0.f;
        #pragma unroll
        for (int d = 0; d < 32; d++) {
            float wv = W1[k * 256 + 32 * h + d];
            sl += wv * al1[h * 32 + d];
            sr += wv * ar1[h * 32 + d];
        }
        W1t[(256 + h) * 256 + k] = f2bf(sl);
        W1t[(264 + h) * 256 + k] = f2bf(sr);
    }
}

// ---------------- GEMM1: [h1 | el1 | er1] = x @ [W1 | wl | wr] via bf16 MFMA ----------------
// block = 256 thr / 4 waves; tile = 64 rows x 272 cols; K-step 32.
#define STR1 40
__global__ __launch_bounds__(256) void gemm1_mfma(const float* __restrict__ x,
                                                  const unsigned short* __restrict__ W1t,
                                                  unsigned short* __restrict__ h,
                                                  float* __restrict__ el1, float* __restrict__ er1, int n) {
    __shared__ unsigned short As[64 * STR1];
    __shared__ unsigned short Bs[272 * STR1];
    int t = threadIdx.x;
    int w = t >> 6, l = t & 63;
    int rb = blockIdx.x * 64;
    f32x4 acc[17] = {};
    int ar = t >> 2;          // A-stage row 0..63
    int ak = (t & 3) * 8;     // A-stage k0
    int lr = w * 16 + (l & 15);  // frag row in LDS
    int lg = l >> 4;             // k-group (contiguous-8 layout: k = 8*g + i)
    for (int kc = 0; kc < 256; kc += 32) {
        {   // stage A (64x32), fp32 -> bf16
            int gr = rb + ar;
            float v[8];
            if (gr < n) {
                f32x4 v0 = *(const f32x4*)&x[(size_t)gr * 256 + kc + ak];
                f32x4 v1 = *(const f32x4*)&x[(size_t)gr * 256 + kc + ak + 4];
                v[0] = v0.x; v[1] = v0.y; v[2] = v0.z; v[3] = v0.w;
                v[4] = v1.x; v[5] = v1.y; v[6] = v1.z; v[7] = v1.w;
            } else {
                #pragma unroll
                for (int i = 0; i < 8; i++) v[i] = 0.f;
            }
            short8 bv;
            #pragma unroll
            for (int i = 0; i < 8; i++) bv[i] = (short)f2bf(v[i]);
            *(short8*)&As[ar * STR1 + ak] = bv;
        }
        #pragma unroll
        for (int i = 0; i < 5; i++) {   // stage B: 272 cols x 32 k = 1088 short8 chunks
            int idx = t + i * 256;
            if (idx < 1088) {
                int bn = idx >> 2;
                int bk = (idx & 3) * 8;
                short8 bv = *(const short8*)&W1t[(size_t)bn * 256 + kc + bk];
                *(short8*)&Bs[bn * STR1 + bk] = bv;
            }
        }
        __syncthreads();
        short8 a = *(short8*)&As[lr * STR1 + lg * 8];
        #pragma unroll
        for (int j = 0; j < 17; j++) {
            short8 b = *(short8*)&Bs[(j * 16 + (l & 15)) * STR1 + lg * 8];
            acc[j] = __builtin_amdgcn_mfma_f32_16x16x32_bf16(a, b, acc[j], 0, 0, 0);
        }
        __syncthreads();
    }
    // epilogue: C layout col = l&15, row = 4*(l>>4)+i
    int r0 = rb + w * 16 + 4 * (l >> 4);
    int c0 = l & 15;
    #pragma unroll
    for (int j = 0; j < 16; j++) {
        #pragma unroll
        for (int i = 0; i < 4; i++) {
            int gr = r0 + i;
            if (gr < n) h[(size_t)gr * 256 + j * 16 + c0] = f2bf(acc[j][i]);
        }
    }
    #pragma unroll
    for (int i = 0; i < 4; i++) {       // j=16: cols 256..271 = [el(8) | er(8)]
        int gr = r0 + i;
        if (gr < n) {
            if (c0 < 8) el1[gr * 8 + c0] = acc[16][i];
            else        er1[gr * 8 + (c0 - 8)] = acc[16][i];
        }
    }
}

// ---------------- layer-1 aggregation + bias + ELU -> x1 (fp32) ----------------
// one wave per node; no max pass (logits bounded ~|e|<2, exp is fp32-safe).
// half-wave per edge, lane owns 8 contiguous dims (bf16x8 = 16B), head = (lane&31)>>2.
// 2 independent edges in flight per half-wave.
__global__ __launch_bounds__(256) void agg1_kernel(const unsigned short* __restrict__ h1b,
                                                   const float* __restrict__ el1,
                                                   const float* __restrict__ er1, const float* __restrict__ b1,
                                                   const int* __restrict__ offs, const int* __restrict__ srt,
                                                   float* __restrict__ x1, int n) {
    int t = threadIdx.x; int lane = t & 63;
    int node = blockIdx.x * 4 + (t >> 6);
    if (node >= n) return;
    int beg = offs[node], end = offs[node + 1];
    int q = lane & 31;          // dim-group: dims [8q, 8q+8)
    int head = q >> 2;
    int half = lane >> 5;
    float er_h = er1[node * 8 + head];
    float acc[8] = {};
    float dsum = 0.f;
    for (int e = beg + half; e < end; e += 4) {
        int sA = srt[e];
        bool hasB = (e + 2) < end;
        int sB = srt[hasB ? e + 2 : e];
        float exA = __expf(el1[sA * 8 + head] + er_h);    // leaky slope 1.0 == identity
        float exB = hasB ? __expf(el1[sB * 8 + head] + er_h) : 0.f;
        short8 hA = *(const short8*)&h1b[(size_t)sA * 256 + q * 8];
        short8 hB = *(const short8*)&h1b[(size_t)sB * 256 + q * 8];
        dsum += exA + exB;
        #pragma unroll
        for (int k = 0; k < 8; k++)
            acc[k] += exA * bf2f((unsigned short)hA[k]) + exB * bf2f((unsigned short)hB[k]);
    }
    dsum += __shfl_xor(dsum, 32);
    #pragma unroll
    for (int k = 0; k < 8; k++) acc[k] += __shfl_xor(acc[k], 32);
    if (half == 0) {
        float inv = dsum > 0.f ? 1.f / dsum : 0.f;
        f32x4 b0 = *(const f32x4*)&b1[q * 8];
        f32x4 b4 = *(const f32x4*)&b1[q * 8 + 4];
        f32x4 o0, o1;
        o0.x = elu_f(acc[0] * inv + b0.x); o0.y = elu_f(acc[1] * inv + b0.y);
        o0.z = elu_f(acc[2] * inv + b0.z); o0.w = elu_f(acc[3] * inv + b0.w);
        o1.x = elu_f(acc[4] * inv + b4.x); o1.y = elu_f(acc[5] * inv + b4.y);
        o1.z = elu_f(acc[6] * inv + b4.z); o1.w = elu_f(acc[7] * inv + b4.w);
        *(f32x4*)&x1[(size_t)node * 256 + q * 8] = o0;
        *(f32x4*)&x1[(size_t)node * 256 + q * 8 + 4] = o1;
    }
}

// ---------------- GEMM2: h2 = x1 @ W2 [N,256]x[256,16] + fused el2/er2 ----------------
__global__ __launch_bounds__(256) void gemm2_kernel(const float* __restrict__ x1, const float* __restrict__ W2,
                                                    const float* __restrict__ al2, const float* __restrict__ ar2,
                                                    float* __restrict__ h2, float* __restrict__ el2,
                                                    float* __restrict__ er2, int n) {
    __shared__ float xs[16][260];
    int t = threadIdx.x;
    int nb = blockIdx.x * 16;
    #pragma unroll
    for (int i = 0; i < 4; i++) {
        int idx = t + i * 256;
        int r = idx >> 6, c4 = idx & 63;
        int gr = nb + r;
        float4 v = make_float4(0.f, 0.f, 0.f, 0.f);
        if (gr < n) v = *(const float4*)&x1[(size_t)gr * 256 + c4 * 4];
        *(float4*)&xs[r][c4 * 4] = v;
    }
    __syncthreads();
    int r = t >> 4, c = t & 15;
    float acc = 0.f;
    #pragma unroll 4
    for (int k = 0; k < 256; k += 4) {
        float4 xv = *(const float4*)&xs[r][k];
        acc += xv.x * W2[(k + 0) * 16 + c] + xv.y * W2[(k + 1) * 16 + c]
             + xv.z * W2[(k + 2) * 16 + c] + xv.w * W2[(k + 3) * 16 + c];
    }
    float pl = acc * al2[c];
    float pr = acc * ar2[c];
    #pragma unroll
    for (int mask = 1; mask < 16; mask <<= 1) {
        pl += __shfl_xor(pl, mask);
        pr += __shfl_xor(pr, mask);
    }
    int gr = nb + r;
    if (gr < n) {
        h2[(size_t)gr * 16 + c] = acc;
        if (c == 0) { el2[gr] = pl; er2[gr] = pr; }
    }
}

// ---------------- layer-2 aggregation + bias + ELU -> out ----------------
// no max pass; 4 edge-groups x 16 dims; 2 edges in flight per group.
__global__ __launch_bounds__(256) void agg2_kernel(const float* __restrict__ h2, const float* __restrict__ el2,
                                                   const float* __restrict__ er2, const float* __restrict__ b2,
                                                   const int* __restrict__ offs, const int* __restrict__ srt,
                                                   float* __restrict__ out, int n) {
    int t = threadIdx.x; int lane = t & 63;
    int node = blockIdx.x * 4 + (t >> 6);
    if (node >= n) return;
    int beg = offs[node], end = offs[node + 1];
    int dim = lane & 15, eg = lane >> 4;
    float er_n = er2[node];
    float acc = 0.f, dsum = 0.f;
    for (int e = beg + eg; e < end; e += 8) {
        int sA = srt[e];
        bool hasB = (e + 4) < end;
        int sB = srt[hasB ? e + 4 : e];
        float evA = el2[sA] + er_n;
        evA = fmaxf(evA, 0.2f * evA);
        float evB = el2[sB] + er_n;
        evB = fmaxf(evB, 0.2f * evB);
        float exA = __expf(evA);
        float exB = hasB ? __expf(evB) : 0.f;
        float hA = h2[(size_t)sA * 16 + dim];
        float hB = h2[(size_t)sB * 16 + dim];
        dsum += exA + exB;
        acc += exA * hA + exB * hB;
    }
    acc += __shfl_xor(acc, 16); acc += __shfl_xor(acc, 32);
    dsum += __shfl_xor(dsum, 16); dsum += __shfl_xor(dsum, 32);
    float inv = dsum > 0.f ? 1.f / dsum : 0.f;
    float o = elu_f(acc * inv + b2[dim]);
    if (lane < 16) out[(size_t)node * 16 + dim] = o;
}

extern "C" void kernel_launch(void* const* d_in, const int* in_sizes, int n_in,
                              void* d_out, int out_size, void* d_ws, size_t ws_size,
                              hipStream_t stream) {
    const float* x   = (const float*)d_in[0];
    const int*   src = (const int*)d_in[1];
    const int*   dst = (const int*)d_in[2];
    const float* W1  = (const float*)d_in[3];
    const float* al1 = (const float*)d_in[4];
    const float* ar1 = (const float*)d_in[5];
    const float* b1  = (const float*)d_in[6];
    const float* W2  = (const float*)d_in[7];
    const float* al2 = (const float*)d_in[8];
    const float* ar2 = (const float*)d_in[9];
    const float* b2  = (const float*)d_in[10];
    const int N = in_sizes[0] / 256;
    const int E = in_sizes[1];

    char* wsp = (char*)d_ws;
    size_t off = 0;
    auto alloc = [&](size_t bytes) -> void* {
        void* p = wsp + off;
        off = (off + bytes + 255) & ~(size_t)255;
        return p;
    };
    unsigned short* h1b = (unsigned short*)alloc((size_t)N * 256 * 2);
    float* x1  = (float*)alloc((size_t)N * 256 * 4);
    float* el1 = (float*)alloc((size_t)N * 8 * 4);
    float* er1 = (float*)alloc((size_t)N * 8 * 4);
    float* h2  = (float*)alloc((size_t)N * 16 * 4);
    float* el2 = (float*)alloc((size_t)N * 4);
    float* er2 = (float*)alloc((size_t)N * 4);
    int*   offs = (int*)alloc((size_t)(N + 1) * 4);
    int*   pos  = (int*)alloc((size_t)N * 4);
    int*   srt  = (int*)alloc((size_t)E * 4);
    unsigned short* W1t = (unsigned short*)alloc((size_t)272 * 256 * 2);

    hipMemsetAsync(pos, 0, (size_t)N * 4, stream);
    count_kernel<<<(E + 255) / 256, 256, 0, stream>>>(dst, pos, E);
    scan_kernel<<<1, 1024, 0, stream>>>(pos, offs, N);
    scatter_kernel<<<(E + 255) / 256, 256, 0, stream>>>(src, dst, pos, srt, E);

    w1t_kernel<<<256, 256, 0, stream>>>(W1, W1t);
    wlr_kernel<<<1, 256, 0, stream>>>(W1, al1, ar1, W1t);
    gemm1_mfma<<<(N + 63) / 64, 256, 0, stream>>>(x, W1t, h1b, el1, er1, N);
    agg1_kernel<<<(N + 3) / 4, 256, 0, stream>>>(h1b, el1, er1, b1, offs, srt, x1, N);
    gemm2_kernel<<<(N + 15) / 16, 256, 0, stream>>>(x1, W2, al2, ar2, h2, el2, er2, N);
    agg2_kernel<<<(N + 3) / 4, 256, 0, stream>>>(h2, el2, er2, b2, offs, srt, (float*)d_out, N);
}

// Round 6
// 252.146 us; speedup vs baseline: 2.0854x; 1.2405x over previous
//
#include <hip/hip_runtime.h>
#include <math.h>

typedef __attribute__((ext_vector_type(8))) short short8;
typedef __attribute__((ext_vector_type(4))) float f32x4;

__device__ __forceinline__ float elu_f(float v) {
    return v > 0.f ? v : __expf(v) - 1.f;
}

__device__ __forceinline__ unsigned short f2bf(float f) {
    unsigned u = __float_as_uint(f);
    unsigned r = (u + 0x7FFF + ((u >> 16) & 1)) >> 16;   // round-to-nearest-even
    return (unsigned short)r;
}

__device__ __forceinline__ float bf2f(unsigned short u) {
    return __uint_as_float(((unsigned)u) << 16);
}

// ---------------- CSR build (by dst) ----------------
__global__ void count_kernel(const int* __restrict__ dst, int* __restrict__ cnt, int E) {
    int e = blockIdx.x * blockDim.x + threadIdx.x;
    if (e < E) atomicAdd(&cnt[dst[e]], 1);
}

// per-1024-chunk sums
__global__ __launch_bounds__(256) void bsum_kernel(const int* __restrict__ cnt, int* __restrict__ bsum, int n) {
    int b = blockIdx.x, t = threadIdx.x;
    int i0 = b * 1024 + t * 4;
    int s = 0;
    #pragma unroll
    for (int k = 0; k < 4; k++) { int i = i0 + k; if (i < n) s += cnt[i]; }
    #pragma unroll
    for (int m = 1; m < 64; m <<= 1) s += __shfl_xor(s, m);
    __shared__ int ws[4];
    if ((t & 63) == 0) ws[t >> 6] = s;
    __syncthreads();
    if (t == 0) bsum[b] = ws[0] + ws[1] + ws[2] + ws[3];
}

// exclusive scan of block sums (nb <= 64, one wave)
__global__ __launch_bounds__(64) void tops_kernel(int* __restrict__ bsum, int nb) {
    int t = threadIdx.x;
    int v = (t < nb) ? bsum[t] : 0;
    int x = v;
    #pragma unroll
    for (int off = 1; off < 64; off <<= 1) {
        int y = __shfl_up(x, off);
        if (t >= off) x += y;
    }
    if (t < nb) bsum[t] = x - v;
}

// rescan each 1024-chunk, add block base; write offs[0..n] and pos (scatter cursor)
__global__ __launch_bounds__(256) void scan_final_kernel(const int* __restrict__ cnt, const int* __restrict__ bbase,
                                                         int* __restrict__ offs, int* __restrict__ pos, int n) {
    int b = blockIdx.x, t = threadIdx.x, lane = t & 63, w = t >> 6;
    int i0 = b * 1024 + t * 4;
    int v[4]; int ts = 0;
    #pragma unroll
    for (int k = 0; k < 4; k++) { int i = i0 + k; v[k] = (i < n) ? cnt[i] : 0; ts += v[k]; }
    int x = ts;
    #pragma unroll
    for (int off = 1; off < 64; off <<= 1) {
        int y = __shfl_up(x, off);
        if (lane >= off) x += y;
    }
    __shared__ int ws[4];
    if (lane == 63) ws[w] = x;
    __syncthreads();
    int wbase = 0;
    #pragma unroll
    for (int k = 0; k < 4; k++) if (k < w) wbase += ws[k];
    int base = bbase[b] + wbase + (x - ts);
    #pragma unroll
    for (int k = 0; k < 4; k++) {
        int i = i0 + k;
        if (i < n) { offs[i] = base; pos[i] = base; }
        base += v[k];
        if (i == n - 1) offs[n] = base;
    }
}

__global__ void scatter_kernel(const int* __restrict__ src, const int* __restrict__ dst,
                               int* __restrict__ pos, int* __restrict__ srt, int E) {
    int e = blockIdx.x * blockDim.x + threadIdx.x;
    if (e < E) {
        int p = atomicAdd(&pos[dst[e]], 1);
        srt[p] = src[e];
    }
}

// ---------------- all weight precompute in one launch ----------------
// blocks 0..255: W1t col b (transpose + bf16)
// block 256:     W1t cols 256..271 = [W1 . al1 heads | W1 . ar1 heads]
// block 257:     W2t [32 cols][256 k]: cols 0..15 = W2^T, 16 = W2.al2, 17 = W2.ar2, 18..31 = 0
__global__ __launch_bounds__(256) void prep_kernel(const float* __restrict__ W1,
                                                   const float* __restrict__ al1, const float* __restrict__ ar1,
                                                   const float* __restrict__ W2,
                                                   const float* __restrict__ al2, const float* __restrict__ ar2,
                                                   unsigned short* __restrict__ W1t,
                                                   unsigned short* __restrict__ W2t) {
    int b = blockIdx.x, t = threadIdx.x;
    if (b < 256) {
        W1t[b * 256 + t] = f2bf(W1[t * 256 + b]);
    } else if (b == 256) {
        int k = t;
        #pragma unroll
        for (int h = 0; h < 8; h++) {
            float sl = 0.f, sr = 0.f;
            #pragma unroll
            for (int d = 0; d < 32; d++) {
                float wv = W1[k * 256 + 32 * h + d];
                sl += wv * al1[h * 32 + d];
                sr += wv * ar1[h * 32 + d];
            }
            W1t[(256 + h) * 256 + k] = f2bf(sl);
            W1t[(264 + h) * 256 + k] = f2bf(sr);
        }
    } else {
        int k = t;
        float sl = 0.f, sr = 0.f;
        #pragma unroll
        for (int c = 0; c < 16; c++) {
            float wv = W2[k * 16 + c];
            W2t[c * 256 + k] = f2bf(wv);
            sl += wv * al2[c];
            sr += wv * ar2[c];
        }
        W2t[16 * 256 + k] = f2bf(sl);
        W2t[17 * 256 + k] = f2bf(sr);
        #pragma unroll
        for (int c = 18; c < 32; c++) W2t[c * 256 + k] = 0;
    }
}

// ---------------- GEMM1: [h1 | el1 | er1] = x @ [W1 | wl | wr] via bf16 MFMA ----------------
#define STR1 40
__global__ __launch_bounds__(256) void gemm1_mfma(const float* __restrict__ x,
                                                  const unsigned short* __restrict__ W1t,
                                                  unsigned short* __restrict__ h,
                                                  float* __restrict__ el1, float* __restrict__ er1, int n) {
    __shared__ unsigned short As[64 * STR1];
    __shared__ unsigned short Bs[272 * STR1];
    int t = threadIdx.x;
    int w = t >> 6, l = t & 63;
    int rb = blockIdx.x * 64;
    f32x4 acc[17] = {};
    int ar = t >> 2;          // A-stage row 0..63
    int ak = (t & 3) * 8;     // A-stage k0
    int lr = w * 16 + (l & 15);
    int lg = l >> 4;
    for (int kc = 0; kc < 256; kc += 32) {
        {   // stage A (64x32), fp32 -> bf16
            int gr = rb + ar;
            float v[8];
            if (gr < n) {
                f32x4 v0 = *(const f32x4*)&x[(size_t)gr * 256 + kc + ak];
                f32x4 v1 = *(const f32x4*)&x[(size_t)gr * 256 + kc + ak + 4];
                v[0] = v0.x; v[1] = v0.y; v[2] = v0.z; v[3] = v0.w;
                v[4] = v1.x; v[5] = v1.y; v[6] = v1.z; v[7] = v1.w;
            } else {
                #pragma unroll
                for (int i = 0; i < 8; i++) v[i] = 0.f;
            }
            short8 bv;
            #pragma unroll
            for (int i = 0; i < 8; i++) bv[i] = (short)f2bf(v[i]);
            *(short8*)&As[ar * STR1 + ak] = bv;
        }
        #pragma unroll
        for (int i = 0; i < 5; i++) {   // stage B: 272 cols x 32 k = 1088 short8 chunks
            int idx = t + i * 256;
            if (idx < 1088) {
                int bn = idx >> 2;
                int bk = (idx & 3) * 8;
                short8 bv = *(const short8*)&W1t[(size_t)bn * 256 + kc + bk];
                *(short8*)&Bs[bn * STR1 + bk] = bv;
            }
        }
        __syncthreads();
        short8 a = *(short8*)&As[lr * STR1 + lg * 8];
        #pragma unroll
        for (int j = 0; j < 17; j++) {
            short8 b = *(short8*)&Bs[(j * 16 + (l & 15)) * STR1 + lg * 8];
            acc[j] = __builtin_amdgcn_mfma_f32_16x16x32_bf16(a, b, acc[j], 0, 0, 0);
        }
        __syncthreads();
    }
    int r0 = rb + w * 16 + 4 * (l >> 4);
    int c0 = l & 15;
    #pragma unroll
    for (int j = 0; j < 16; j++) {
        #pragma unroll
        for (int i = 0; i < 4; i++) {
            int gr = r0 + i;
            if (gr < n) h[(size_t)gr * 256 + j * 16 + c0] = f2bf(acc[j][i]);
        }
    }
    #pragma unroll
    for (int i = 0; i < 4; i++) {       // j=16: cols 256..271 = [el(8) | er(8)]
        int gr = r0 + i;
        if (gr < n) {
            if (c0 < 8) el1[gr * 8 + c0] = acc[16][i];
            else        er1[gr * 8 + (c0 - 8)] = acc[16][i];
        }
    }
}

// ---------------- layer-1 aggregation + bias + ELU -> x1 (bf16) ----------------
// one wave per node; no max pass (logits |e| < ~2, fp32 exp safe; empty segment -> bias).
// half-wave per edge, lane owns 8 contiguous dims; head = (lane&31)>>2; 4 edges in flight/half.
__global__ __launch_bounds__(256) void agg1_kernel(const unsigned short* __restrict__ h1b,
                                                   const float* __restrict__ el1,
                                                   const float* __restrict__ er1, const float* __restrict__ b1,
                                                   const int* __restrict__ offs, const int* __restrict__ srt,
                                                   unsigned short* __restrict__ x1b, int n) {
    int t = threadIdx.x; int lane = t & 63;
    int node = blockIdx.x * 4 + (t >> 6);
    if (node >= n) return;
    int beg = offs[node], end = offs[node + 1];
    int q = lane & 31;          // dim-group: dims [8q, 8q+8)
    int head = q >> 2;
    int half = lane >> 5;
    float er_h = er1[node * 8 + head];
    float acc[8] = {};
    float dsum = 0.f;
    for (int e = beg + half; e < end; e += 8) {
        int eB = e + 2, eC = e + 4, eD = e + 6;
        bool hB = eB < end, hC = eC < end, hD = eD < end;
        int sA = srt[e];
        int sB = srt[hB ? eB : e];
        int sC = srt[hC ? eC : e];
        int sD = srt[hD ? eD : e];
        float exA = __expf(el1[sA * 8 + head] + er_h);          // leaky slope 1.0 == identity
        float exB = hB ? __expf(el1[sB * 8 + head] + er_h) : 0.f;
        float exC = hC ? __expf(el1[sC * 8 + head] + er_h) : 0.f;
        float exD = hD ? __expf(el1[sD * 8 + head] + er_h) : 0.f;
        short8 hA = *(const short8*)&h1b[(size_t)sA * 256 + q * 8];
        short8 hBv = *(const short8*)&h1b[(size_t)sB * 256 + q * 8];
        short8 hCv = *(const short8*)&h1b[(size_t)sC * 256 + q * 8];
        short8 hDv = *(const short8*)&h1b[(size_t)sD * 256 + q * 8];
        dsum += (exA + exB) + (exC + exD);
        #pragma unroll
        for (int k = 0; k < 8; k++)
            acc[k] += exA * bf2f((unsigned short)hA[k]) + exB * bf2f((unsigned short)hBv[k])
                    + exC * bf2f((unsigned short)hCv[k]) + exD * bf2f((unsigned short)hDv[k]);
    }
    dsum += __shfl_xor(dsum, 32);
    #pragma unroll
    for (int k = 0; k < 8; k++) acc[k] += __shfl_xor(acc[k], 32);
    if (half == 0) {
        float inv = dsum > 0.f ? 1.f / dsum : 0.f;
        f32x4 b0 = *(const f32x4*)&b1[q * 8];
        f32x4 b4 = *(const f32x4*)&b1[q * 8 + 4];
        float o[8];
        o[0] = elu_f(acc[0] * inv + b0.x); o[1] = elu_f(acc[1] * inv + b0.y);
        o[2] = elu_f(acc[2] * inv + b0.z); o[3] = elu_f(acc[3] * inv + b0.w);
        o[4] = elu_f(acc[4] * inv + b4.x); o[5] = elu_f(acc[5] * inv + b4.y);
        o[6] = elu_f(acc[6] * inv + b4.z); o[7] = elu_f(acc[7] * inv + b4.w);
        short8 ov;
        #pragma unroll
        for (int k = 0; k < 8; k++) ov[k] = (short)f2bf(o[k]);
        *(short8*)&x1b[(size_t)node * 256 + q * 8] = ov;
    }
}

// ---------------- GEMM2: [h2 | el2 | er2] = x1 @ [W2 | wl2 | wr2] via bf16 MFMA ----------------
// tile 64 rows x 32 cols (2 j-tiles); cols 18..31 are zero padding.
__global__ __launch_bounds__(256) void gemm2_mfma(const unsigned short* __restrict__ x1b,
                                                  const unsigned short* __restrict__ W2t,
                                                  float* __restrict__ h2, float* __restrict__ el2,
                                                  float* __restrict__ er2, int n) {
    __shared__ unsigned short As[64 * STR1];
    __shared__ unsigned short Bs[32 * STR1];
    int t = threadIdx.x;
    int w = t >> 6, l = t & 63;
    int rb = blockIdx.x * 64;
    f32x4 acc[2] = {};
    int ar = t >> 2;
    int ak = (t & 3) * 8;
    int lr = w * 16 + (l & 15);
    int lg = l >> 4;
    for (int kc = 0; kc < 256; kc += 32) {
        {
            int gr = rb + ar;
            short8 av = {0, 0, 0, 0, 0, 0, 0, 0};
            if (gr < n) av = *(const short8*)&x1b[(size_t)gr * 256 + kc + ak];
            *(short8*)&As[ar * STR1 + ak] = av;
        }
        if (t < 128) {   // 32 cols x 4 chunks
            int bn = t >> 2, bk = (t & 3) * 8;
            short8 bv = *(const short8*)&W2t[(size_t)bn * 256 + kc + bk];
            *(short8*)&Bs[bn * STR1 + bk] = bv;
        }
        __syncthreads();
        short8 a = *(short8*)&As[lr * STR1 + lg * 8];
        #pragma unroll
        for (int j = 0; j < 2; j++) {
            short8 b = *(short8*)&Bs[(j * 16 + (l & 15)) * STR1 + lg * 8];
            acc[j] = __builtin_amdgcn_mfma_f32_16x16x32_bf16(a, b, acc[j], 0, 0, 0);
        }
        __syncthreads();
    }
    int r0 = rb + w * 16 + 4 * (l >> 4);
    int c0 = l & 15;
    #pragma unroll
    for (int i = 0; i < 4; i++) {
        int gr = r0 + i;
        if (gr < n) {
            h2[(size_t)gr * 16 + c0] = acc[0][i];
            if (c0 == 0) el2[gr] = acc[1][i];        // col 16
            else if (c0 == 1) er2[gr] = acc[1][i];   // col 17
        }
    }
}

// ---------------- layer-2 aggregation + bias + ELU -> out ----------------
__global__ __launch_bounds__(256) void agg2_kernel(const float* __restrict__ h2, const float* __restrict__ el2,
                                                   const float* __restrict__ er2, const float* __restrict__ b2,
                                                   const int* __restrict__ offs, const int* __restrict__ srt,
                                                   float* __restrict__ out, int n) {
    int t = threadIdx.x; int lane = t & 63;
    int node = blockIdx.x * 4 + (t >> 6);
    if (node >= n) return;
    int beg = offs[node], end = offs[node + 1];
    int dim = lane & 15, eg = lane >> 4;
    float er_n = er2[node];
    float acc = 0.f, dsum = 0.f;
    for (int e = beg + eg; e < end; e += 8) {
        int sA = srt[e];
        bool hasB = (e + 4) < end;
        int sB = srt[hasB ? e + 4 : e];
        float evA = el2[sA] + er_n;
        evA = fmaxf(evA, 0.2f * evA);
        float evB = el2[sB] + er_n;
        evB = fmaxf(evB, 0.2f * evB);
        float exA = __expf(evA);
        float exB = hasB ? __expf(evB) : 0.f;
        float hA = h2[(size_t)sA * 16 + dim];
        float hB = h2[(size_t)sB * 16 + dim];
        dsum += exA + exB;
        acc += exA * hA + exB * hB;
    }
    acc += __shfl_xor(acc, 16); acc += __shfl_xor(acc, 32);
    dsum += __shfl_xor(dsum, 16); dsum += __shfl_xor(dsum, 32);
    float inv = dsum > 0.f ? 1.f / dsum : 0.f;
    float o = elu_f(acc * inv + b2[dim]);
    if (lane < 16) out[(size_t)node * 16 + dim] = o;
}

extern "C" void kernel_launch(void* const* d_in, const int* in_sizes, int n_in,
                              void* d_out, int out_size, void* d_ws, size_t ws_size,
                              hipStream_t stream) {
    const float* x   = (const float*)d_in[0];
    const int*   src = (const int*)d_in[1];
    const int*   dst = (const int*)d_in[2];
    const float* W1  = (const float*)d_in[3];
    const float* al1 = (const float*)d_in[4];
    const float* ar1 = (const float*)d_in[5];
    const float* b1  = (const float*)d_in[6];
    const float* W2  = (const float*)d_in[7];
    const float* al2 = (const float*)d_in[8];
    const float* ar2 = (const float*)d_in[9];
    const float* b2  = (const float*)d_in[10];
    const int N = in_sizes[0] / 256;
    const int E = in_sizes[1];

    char* wsp = (char*)d_ws;
    size_t off = 0;
    auto alloc = [&](size_t bytes) -> void* {
        void* p = wsp + off;
        off = (off + bytes + 255) & ~(size_t)255;
        return p;
    };
    unsigned short* h1b = (unsigned short*)alloc((size_t)N * 256 * 2);
    unsigned short* x1b = (unsigned short*)alloc((size_t)N * 256 * 2);
    float* el1 = (float*)alloc((size_t)N * 8 * 4);
    float* er1 = (float*)alloc((size_t)N * 8 * 4);
    float* h2  = (float*)alloc((size_t)N * 16 * 4);
    float* el2 = (float*)alloc((size_t)N * 4);
    float* er2 = (float*)alloc((size_t)N * 4);
    int*   offs = (int*)alloc((size_t)(N + 1) * 4);
    int*   pos  = (int*)alloc((size_t)N * 4);
    int*   cnt  = (int*)alloc((size_t)N * 4);
    int*   bsum = (int*)alloc((size_t)64 * 4);
    int*   srt  = (int*)alloc((size_t)E * 4);
    unsigned short* W1t = (unsigned short*)alloc((size_t)272 * 256 * 2);
    unsigned short* W2t = (unsigned short*)alloc((size_t)32 * 256 * 2);

    const int NB = (N + 1023) / 1024;   // scan chunks (<= 64)

    (void)hipMemsetAsync(cnt, 0, (size_t)N * 4, stream);
    count_kernel<<<(E + 255) / 256, 256, 0, stream>>>(dst, cnt, E);
    bsum_kernel<<<NB, 256, 0, stream>>>(cnt, bsum, N);
    tops_kernel<<<1, 64, 0, stream>>>(bsum, NB);
    scan_final_kernel<<<NB, 256, 0, stream>>>(cnt, bsum, offs, pos, N);
    scatter_kernel<<<(E + 255) / 256, 256, 0, stream>>>(src, dst, pos, srt, E);

    prep_kernel<<<258, 256, 0, stream>>>(W1, al1, ar1, W2, al2, ar2, W1t, W2t);
    gemm1_mfma<<<(N + 63) / 64, 256, 0, stream>>>(x, W1t, h1b, el1, er1, N);
    agg1_kernel<<<(N + 3) / 4, 256, 0, stream>>>(h1b, el1, er1, b1, offs, srt, x1b, N);
    gemm2_mfma<<<(N + 63) / 64, 256, 0, stream>>>(x1b, W2t, h2, el2, er2, N);
    agg2_kernel<<<(N + 3) / 4, 256, 0, stream>>>(h2, el2, er2, b2, offs, srt, (float*)d_out, N);
}

// Round 7
// 216.316 us; speedup vs baseline: 2.4308x; 1.1656x over previous
//
#include <hip/hip_runtime.h>
#include <math.h>

typedef __attribute__((ext_vector_type(8))) short short8;
typedef __attribute__((ext_vector_type(4))) float f32x4;

__device__ __forceinline__ float elu_f(float v) {
    return v > 0.f ? v : __expf(v) - 1.f;
}

__device__ __forceinline__ unsigned short f2bf(float f) {
    unsigned u = __float_as_uint(f);
    unsigned r = (u + 0x7FFF + ((u >> 16) & 1)) >> 16;   // round-to-nearest-even
    return (unsigned short)r;
}

__device__ __forceinline__ float bf2f(unsigned short u) {
    return __uint_as_float(((unsigned)u) << 16);
}

// ---------------- fused: edge count (by dst) + weight precompute ----------------
// blocks [0, nCB): count 4 edges/thread
// blocks [nCB, nCB+256): W1t col (transpose + bf16)
// block nCB+256: W1t cols 256..271 = [W1.al1 | W1.ar1]
// block nCB+257: W2t 32 cols: 0..15 = W2^T, 16 = W2.al2, 17 = W2.ar2, 18..31 = 0
__global__ __launch_bounds__(256) void count_prep_kernel(const int* __restrict__ dst, int* __restrict__ cnt,
                                                         int E, int nCB,
                                                         const float* __restrict__ W1,
                                                         const float* __restrict__ al1, const float* __restrict__ ar1,
                                                         const float* __restrict__ W2,
                                                         const float* __restrict__ al2, const float* __restrict__ ar2,
                                                         unsigned short* __restrict__ W1t,
                                                         unsigned short* __restrict__ W2t) {
    int b = blockIdx.x, t = threadIdx.x;
    if (b < nCB) {
        int e0 = (b * 256 + t) * 4;
        if (e0 + 3 < E) {
            int4 d4 = *(const int4*)&dst[e0];
            atomicAdd(&cnt[d4.x], 1);
            atomicAdd(&cnt[d4.y], 1);
            atomicAdd(&cnt[d4.z], 1);
            atomicAdd(&cnt[d4.w], 1);
        } else {
            for (int e = e0; e < E; e++) atomicAdd(&cnt[dst[e]], 1);
        }
        return;
    }
    int bb = b - nCB;
    if (bb < 256) {
        W1t[bb * 256 + t] = f2bf(W1[t * 256 + bb]);
    } else if (bb == 256) {
        int k = t;
        #pragma unroll
        for (int h = 0; h < 8; h++) {
            float sl = 0.f, sr = 0.f;
            #pragma unroll
            for (int d = 0; d < 32; d++) {
                float wv = W1[k * 256 + 32 * h + d];
                sl += wv * al1[h * 32 + d];
                sr += wv * ar1[h * 32 + d];
            }
            W1t[(256 + h) * 256 + k] = f2bf(sl);
            W1t[(264 + h) * 256 + k] = f2bf(sr);
        }
    } else {
        int k = t;
        float sl = 0.f, sr = 0.f;
        #pragma unroll
        for (int c = 0; c < 16; c++) {
            float wv = W2[k * 16 + c];
            W2t[c * 256 + k] = f2bf(wv);
            sl += wv * al2[c];
            sr += wv * ar2[c];
        }
        W2t[16 * 256 + k] = f2bf(sl);
        W2t[17 * 256 + k] = f2bf(sr);
        #pragma unroll
        for (int c = 18; c < 32; c++) W2t[c * 256 + k] = 0;
    }
}

// per-1024-chunk sums
__global__ __launch_bounds__(256) void bsum_kernel(const int* __restrict__ cnt, int* __restrict__ bsum, int n) {
    int b = blockIdx.x, t = threadIdx.x;
    int i0 = b * 1024 + t * 4;
    int s = 0;
    #pragma unroll
    for (int k = 0; k < 4; k++) { int i = i0 + k; if (i < n) s += cnt[i]; }
    #pragma unroll
    for (int m = 1; m < 64; m <<= 1) s += __shfl_xor(s, m);
    __shared__ int ws[4];
    if ((t & 63) == 0) ws[t >> 6] = s;
    __syncthreads();
    if (t == 0) bsum[b] = ws[0] + ws[1] + ws[2] + ws[3];
}

// rescan each 1024-chunk; block-sum prefix recomputed locally (nb <= 64); writes offs[0..n] and pos
__global__ __launch_bounds__(256) void scan_final_kernel(const int* __restrict__ cnt, const int* __restrict__ bsum,
                                                         int* __restrict__ offs, int* __restrict__ pos,
                                                         int n, int nb) {
    int b = blockIdx.x, t = threadIdx.x, lane = t & 63, w = t >> 6;
    __shared__ int ws[4];
    __shared__ int bbase_s;
    int i0 = b * 1024 + t * 4;
    int v[4]; int ts = 0;
    #pragma unroll
    for (int k = 0; k < 4; k++) { int i = i0 + k; v[k] = (i < n) ? cnt[i] : 0; ts += v[k]; }
    int x = ts;
    #pragma unroll
    for (int off = 1; off < 64; off <<= 1) {
        int y = __shfl_up(x, off);
        if (lane >= off) x += y;
    }
    if (lane == 63) ws[w] = x;
    if (w == 0) {   // exclusive prefix of block sums up to b, in wave 0
        int bv = (lane < nb) ? bsum[lane] : 0;
        int bx = bv;
        #pragma unroll
        for (int off = 1; off < 64; off <<= 1) {
            int y = __shfl_up(bx, off);
            if (lane >= off) bx += y;
        }
        if (lane == b) bbase_s = bx - bv;
    }
    __syncthreads();
    int wbase = 0;
    #pragma unroll
    for (int k = 0; k < 4; k++) if (k < w) wbase += ws[k];
    int base = bbase_s + wbase + (x - ts);
    #pragma unroll
    for (int k = 0; k < 4; k++) {
        int i = i0 + k;
        if (i < n) { offs[i] = base; pos[i] = base; }
        base += v[k];
        if (i == n - 1) offs[n] = base;
    }
}

__global__ __launch_bounds__(256) void scatter_kernel(const int* __restrict__ src, const int* __restrict__ dst,
                                                      int* __restrict__ pos, int* __restrict__ srt, int E) {
    int e0 = (blockIdx.x * 256 + threadIdx.x) * 4;
    if (e0 + 3 < E) {
        int4 s4 = *(const int4*)&src[e0];
        int4 d4 = *(const int4*)&dst[e0];
        int p;
        p = atomicAdd(&pos[d4.x], 1); srt[p] = s4.x;
        p = atomicAdd(&pos[d4.y], 1); srt[p] = s4.y;
        p = atomicAdd(&pos[d4.z], 1); srt[p] = s4.z;
        p = atomicAdd(&pos[d4.w], 1); srt[p] = s4.w;
    } else {
        for (int e = e0; e < E; e++) {
            int p = atomicAdd(&pos[dst[e]], 1);
            srt[p] = src[e];
        }
    }
}

// ---------------- GEMM1: [h1 | el1 | er1] = x @ [W1 | wl | wr] via bf16 MFMA ----------------
// 512 thr / 8 waves; tile = 128 rows x 272 cols; K-step 32.
#define STR1 40
__global__ __launch_bounds__(512) void gemm1_mfma(const float* __restrict__ x,
                                                  const unsigned short* __restrict__ W1t,
                                                  unsigned short* __restrict__ h,
                                                  float* __restrict__ el1, float* __restrict__ er1, int n) {
    __shared__ unsigned short As[128 * STR1];
    __shared__ unsigned short Bs[272 * STR1];
    int t = threadIdx.x;
    int w = t >> 6, l = t & 63;
    int rb = blockIdx.x * 128;
    f32x4 acc[17] = {};
    int ar = t >> 2;          // A-stage row 0..127
    int ak = (t & 3) * 8;     // A-stage k0
    int lr = w * 16 + (l & 15);
    int lg = l >> 4;
    for (int kc = 0; kc < 256; kc += 32) {
        {   // stage A (128x32), fp32 -> bf16
            int gr = rb + ar;
            float v[8];
            if (gr < n) {
                f32x4 v0 = *(const f32x4*)&x[(size_t)gr * 256 + kc + ak];
                f32x4 v1 = *(const f32x4*)&x[(size_t)gr * 256 + kc + ak + 4];
                v[0] = v0.x; v[1] = v0.y; v[2] = v0.z; v[3] = v0.w;
                v[4] = v1.x; v[5] = v1.y; v[6] = v1.z; v[7] = v1.w;
            } else {
                #pragma unroll
                for (int i = 0; i < 8; i++) v[i] = 0.f;
            }
            short8 bv;
            #pragma unroll
            for (int i = 0; i < 8; i++) bv[i] = (short)f2bf(v[i]);
            *(short8*)&As[ar * STR1 + ak] = bv;
        }
        #pragma unroll
        for (int i = 0; i < 3; i++) {   // stage B: 272 cols x 4 chunks = 1088
            int idx = t + i * 512;
            if (idx < 1088) {
                int bn = idx >> 2;
                int bk = (idx & 3) * 8;
                short8 bv = *(const short8*)&W1t[(size_t)bn * 256 + kc + bk];
                *(short8*)&Bs[bn * STR1 + bk] = bv;
            }
        }
        __syncthreads();
        short8 a = *(short8*)&As[lr * STR1 + lg * 8];
        #pragma unroll
        for (int j = 0; j < 17; j++) {
            short8 b = *(short8*)&Bs[(j * 16 + (l & 15)) * STR1 + lg * 8];
            acc[j] = __builtin_amdgcn_mfma_f32_16x16x32_bf16(a, b, acc[j], 0, 0, 0);
        }
        __syncthreads();
    }
    int r0 = rb + w * 16 + 4 * (l >> 4);
    int c0 = l & 15;
    #pragma unroll
    for (int j = 0; j < 16; j++) {
        #pragma unroll
        for (int i = 0; i < 4; i++) {
            int gr = r0 + i;
            if (gr < n) h[(size_t)gr * 256 + j * 16 + c0] = f2bf(acc[j][i]);
        }
    }
    #pragma unroll
    for (int i = 0; i < 4; i++) {       // j=16: cols 256..271 = [el(8) | er(8)]
        int gr = r0 + i;
        if (gr < n) {
            if (c0 < 8) el1[gr * 8 + c0] = acc[16][i];
            else        er1[gr * 8 + (c0 - 8)] = acc[16][i];
        }
    }
}

// ---------------- layer-1 aggregation + bias + ELU -> x1 (bf16) ----------------
__global__ __launch_bounds__(256) void agg1_kernel(const unsigned short* __restrict__ h1b,
                                                   const float* __restrict__ el1,
                                                   const float* __restrict__ er1, const float* __restrict__ b1,
                                                   const int* __restrict__ offs, const int* __restrict__ srt,
                                                   unsigned short* __restrict__ x1b, int n) {
    int t = threadIdx.x; int lane = t & 63;
    int node = blockIdx.x * 4 + (t >> 6);
    if (node >= n) return;
    int beg = offs[node], end = offs[node + 1];
    int q = lane & 31;          // dim-group: dims [8q, 8q+8)
    int head = q >> 2;
    int half = lane >> 5;
    float er_h = er1[node * 8 + head];
    float acc[8] = {};
    float dsum = 0.f;
    for (int e = beg + half; e < end; e += 8) {
        int eB = e + 2, eC = e + 4, eD = e + 6;
        bool hB = eB < end, hC = eC < end, hD = eD < end;
        int sA = srt[e];
        int sB = srt[hB ? eB : e];
        int sC = srt[hC ? eC : e];
        int sD = srt[hD ? eD : e];
        float exA = __expf(el1[sA * 8 + head] + er_h);          // leaky slope 1.0 == identity
        float exB = hB ? __expf(el1[sB * 8 + head] + er_h) : 0.f;
        float exC = hC ? __expf(el1[sC * 8 + head] + er_h) : 0.f;
        float exD = hD ? __expf(el1[sD * 8 + head] + er_h) : 0.f;
        short8 hA = *(const short8*)&h1b[(size_t)sA * 256 + q * 8];
        short8 hBv = *(const short8*)&h1b[(size_t)sB * 256 + q * 8];
        short8 hCv = *(const short8*)&h1b[(size_t)sC * 256 + q * 8];
        short8 hDv = *(const short8*)&h1b[(size_t)sD * 256 + q * 8];
        dsum += (exA + exB) + (exC + exD);
        #pragma unroll
        for (int k = 0; k < 8; k++)
            acc[k] += exA * bf2f((unsigned short)hA[k]) + exB * bf2f((unsigned short)hBv[k])
                    + exC * bf2f((unsigned short)hCv[k]) + exD * bf2f((unsigned short)hDv[k]);
    }
    dsum += __shfl_xor(dsum, 32);
    #pragma unroll
    for (int k = 0; k < 8; k++) acc[k] += __shfl_xor(acc[k], 32);
    if (half == 0) {
        float inv = dsum > 0.f ? 1.f / dsum : 0.f;
        f32x4 b0 = *(const f32x4*)&b1[q * 8];
        f32x4 b4 = *(const f32x4*)&b1[q * 8 + 4];
        float o[8];
        o[0] = elu_f(acc[0] * inv + b0.x); o[1] = elu_f(acc[1] * inv + b0.y);
        o[2] = elu_f(acc[2] * inv + b0.z); o[3] = elu_f(acc[3] * inv + b0.w);
        o[4] = elu_f(acc[4] * inv + b4.x); o[5] = elu_f(acc[5] * inv + b4.y);
        o[6] = elu_f(acc[6] * inv + b4.z); o[7] = elu_f(acc[7] * inv + b4.w);
        short8 ov;
        #pragma unroll
        for (int k = 0; k < 8; k++) ov[k] = (short)f2bf(o[k]);
        *(short8*)&x1b[(size_t)node * 256 + q * 8] = ov;
    }
}

// ---------------- GEMM2: [h2 | el2 | er2] = x1 @ [W2 | wl2 | wr2] via bf16 MFMA ----------------
__global__ __launch_bounds__(256) void gemm2_mfma(const unsigned short* __restrict__ x1b,
                                                  const unsigned short* __restrict__ W2t,
                                                  float* __restrict__ h2, float* __restrict__ el2,
                                                  float* __restrict__ er2, int n) {
    __shared__ unsigned short As[64 * STR1];
    __shared__ unsigned short Bs[32 * STR1];
    int t = threadIdx.x;
    int w = t >> 6, l = t & 63;
    int rb = blockIdx.x * 64;
    f32x4 acc[2] = {};
    int ar = t >> 2;
    int ak = (t & 3) * 8;
    int lr = w * 16 + (l & 15);
    int lg = l >> 4;
    for (int kc = 0; kc < 256; kc += 32) {
        {
            int gr = rb + ar;
            short8 av = {0, 0, 0, 0, 0, 0, 0, 0};
            if (gr < n) av = *(const short8*)&x1b[(size_t)gr * 256 + kc + ak];
            *(short8*)&As[ar * STR1 + ak] = av;
        }
        if (t < 128) {   // 32 cols x 4 chunks
            int bn = t >> 2, bk = (t & 3) * 8;
            short8 bv = *(const short8*)&W2t[(size_t)bn * 256 + kc + bk];
            *(short8*)&Bs[bn * STR1 + bk] = bv;
        }
        __syncthreads();
        short8 a = *(short8*)&As[lr * STR1 + lg * 8];
        #pragma unroll
        for (int j = 0; j < 2; j++) {
            short8 b = *(short8*)&Bs[(j * 16 + (l & 15)) * STR1 + lg * 8];
            acc[j] = __builtin_amdgcn_mfma_f32_16x16x32_bf16(a, b, acc[j], 0, 0, 0);
        }
        __syncthreads();
    }
    int r0 = rb + w * 16 + 4 * (l >> 4);
    int c0 = l & 15;
    #pragma unroll
    for (int i = 0; i < 4; i++) {
        int gr = r0 + i;
        if (gr < n) {
            h2[(size_t)gr * 16 + c0] = acc[0][i];
            if (c0 == 0) el2[gr] = acc[1][i];        // col 16
            else if (c0 == 1) er2[gr] = acc[1][i];   // col 17
        }
    }
}

// ---------------- layer-2 aggregation + bias + ELU -> out ----------------
// 4 edge-groups x 16 dims; 4 edges in flight per group.
__global__ __launch_bounds__(256) void agg2_kernel(const float* __restrict__ h2, const float* __restrict__ el2,
                                                   const float* __restrict__ er2, const float* __restrict__ b2,
                                                   const int* __restrict__ offs, const int* __restrict__ srt,
                                                   float* __restrict__ out, int n) {
    int t = threadIdx.x; int lane = t & 63;
    int node = blockIdx.x * 4 + (t >> 6);
    if (node >= n) return;
    int beg = offs[node], end = offs[node + 1];
    int dim = lane & 15, eg = lane >> 4;
    float er_n = er2[node];
    float acc = 0.f, dsum = 0.f;
    for (int e = beg + eg; e < end; e += 16) {
        int eB = e + 4, eC = e + 8, eD = e + 12;
        bool hB = eB < end, hC = eC < end, hD = eD < end;
        int sA = srt[e];
        int sB = srt[hB ? eB : e];
        int sC = srt[hC ? eC : e];
        int sD = srt[hD ? eD : e];
        float evA = el2[sA] + er_n; evA = fmaxf(evA, 0.2f * evA);
        float evB = el2[sB] + er_n; evB = fmaxf(evB, 0.2f * evB);
        float evC = el2[sC] + er_n; evC = fmaxf(evC, 0.2f * evC);
        float evD = el2[sD] + er_n; evD = fmaxf(evD, 0.2f * evD);
        float exA = __expf(evA);
        float exB = hB ? __expf(evB) : 0.f;
        float exC = hC ? __expf(evC) : 0.f;
        float exD = hD ? __expf(evD) : 0.f;
        float hA = h2[(size_t)sA * 16 + dim];
        float hBv = h2[(size_t)sB * 16 + dim];
        float hCv = h2[(size_t)sC * 16 + dim];
        float hDv = h2[(size_t)sD * 16 + dim];
        dsum += (exA + exB) + (exC + exD);
        acc += exA * hA + exB * hBv + exC * hCv + exD * hDv;
    }
    acc += __shfl_xor(acc, 16); acc += __shfl_xor(acc, 32);
    dsum += __shfl_xor(dsum, 16); dsum += __shfl_xor(dsum, 32);
    float inv = dsum > 0.f ? 1.f / dsum : 0.f;
    float o = elu_f(acc * inv + b2[dim]);
    if (lane < 16) out[(size_t)node * 16 + dim] = o;
}

extern "C" void kernel_launch(void* const* d_in, const int* in_sizes, int n_in,
                              void* d_out, int out_size, void* d_ws, size_t ws_size,
                              hipStream_t stream) {
    const float* x   = (const float*)d_in[0];
    const int*   src = (const int*)d_in[1];
    const int*   dst = (const int*)d_in[2];
    const float* W1  = (const float*)d_in[3];
    const float* al1 = (const float*)d_in[4];
    const float* ar1 = (const float*)d_in[5];
    const float* b1  = (const float*)d_in[6];
    const float* W2  = (const float*)d_in[7];
    const float* al2 = (const float*)d_in[8];
    const float* ar2 = (const float*)d_in[9];
    const float* b2  = (const float*)d_in[10];
    const int N = in_sizes[0] / 256;
    const int E = in_sizes[1];

    char* wsp = (char*)d_ws;
    size_t off = 0;
    auto alloc = [&](size_t bytes) -> void* {
        void* p = wsp + off;
        off = (off + bytes + 255) & ~(size_t)255;
        return p;
    };
    unsigned short* h1b = (unsigned short*)alloc((size_t)N * 256 * 2);
    unsigned short* x1b = (unsigned short*)alloc((size_t)N * 256 * 2);
    float* el1 = (float*)alloc((size_t)N * 8 * 4);
    float* er1 = (float*)alloc((size_t)N * 8 * 4);
    float* h2  = (float*)alloc((size_t)N * 16 * 4);
    float* el2 = (float*)alloc((size_t)N * 4);
    float* er2 = (float*)alloc((size_t)N * 4);
    int*   offs = (int*)alloc((size_t)(N + 1) * 4);
    int*   pos  = (int*)alloc((size_t)N * 4);
    int*   cnt  = (int*)alloc((size_t)N * 4);
    int*   bsum = (int*)alloc((size_t)64 * 4);
    int*   srt  = (int*)alloc((size_t)E * 4);
    unsigned short* W1t = (unsigned short*)alloc((size_t)272 * 256 * 2);
    unsigned short* W2t = (unsigned short*)alloc((size_t)32 * 256 * 2);

    const int NB  = (N + 1023) / 1024;   // scan chunks (<= 64)
    const int nCB = (E + 1023) / 1024;   // count blocks (4 edges/thread)

    (void)hipMemsetAsync(cnt, 0, (size_t)N * 4, stream);
    count_prep_kernel<<<nCB + 258, 256, 0, stream>>>(dst, cnt, E, nCB,
                                                     W1, al1, ar1, W2, al2, ar2, W1t, W2t);
    bsum_kernel<<<NB, 256, 0, stream>>>(cnt, bsum, N);
    scan_final_kernel<<<NB, 256, 0, stream>>>(cnt, bsum, offs, pos, N, NB);
    scatter_kernel<<<(E + 1023) / 1024, 256, 0, stream>>>(src, dst, pos, srt, E);

    gemm1_mfma<<<(N + 127) / 128, 512, 0, stream>>>(x, W1t, h1b, el1, er1, N);
    agg1_kernel<<<(N + 3) / 4, 256, 0, stream>>>(h1b, el1, er1, b1, offs, srt, x1b, N);
    gemm2_mfma<<<(N + 63) / 64, 256, 0, stream>>>(x1b, W2t, h2, el2, er2, N);
    agg2_kernel<<<(N + 3) / 4, 256, 0, stream>>>(h2, el2, er2, b2, offs, srt, (float*)d_out, N);
}